// Round 7
// baseline (329.099 us; speedup 1.0000x reference)
//
#include <hip/hip_runtime.h>
#include <hip/hip_bf16.h>
#include <math.h>

// ---------------- problem constants ----------------
#define T_TOK 2048
#define H_DIM 512
#define E_NUM 16
#define TOPK  2
#define I_DIM 2048
#define IS_DIM 1024
#define NROWS (T_TOK * TOPK)
#define RPMAX 5120             // padded grouped rows upper bound
#define NRG   (RPMAX / 64)     // 80 rowgroups

typedef __attribute__((ext_vector_type(8))) short bf16x8;
typedef __attribute__((ext_vector_type(4))) float f32x4;
typedef unsigned short ushort_t;

static __device__ __forceinline__ unsigned short f2bf(float f) {
  unsigned int u = __float_as_uint(f);
  unsigned int r = (u + 0x7fffu + ((u >> 16) & 1u)) >> 16;   // RNE
  return (unsigned short)r;
}

static __device__ __forceinline__ bf16x8 pack8(float4 a, float4 b) {
  bf16x8 v;
  v[0] = (short)f2bf(a.x); v[1] = (short)f2bf(a.y);
  v[2] = (short)f2bf(a.z); v[3] = (short)f2bf(a.w);
  v[4] = (short)f2bf(b.x); v[5] = (short)f2bf(b.y);
  v[6] = (short)f2bf(b.z); v[7] = (short)f2bf(b.w);
  return v;
}

// ================= fragment-major (FM) layout =================
// M[R][K] row-major -> chunk c = rg*(K/32) + kk; lane l holds
// M[rg*16 + (l&15)][kk*32 + (l>>4)*8 .. +8] (one bf16x8, 16B).
// A wave reading one chunk = ONE contiguous 1KB load.

// ---------------- weights fp32 row-major -> FM bf16 (coalesced reads) --------
template <int LKC>
__global__ __launch_bounds__(256) void permw_kernel(const float* __restrict__ s,
                                                    ushort_t* __restrict__ d, int n8) {
  const int KC = 1 << LKC;
  const int LQ = LKC + 2;             // 8-elem units per row = 4*KC
  int i = blockIdx.x * 256 + threadIdx.x;
  int stride = gridDim.x * 256;
  for (; i < n8; i += stride) {
    int row = i >> LQ;
    int q   = i & ((1 << LQ) - 1);
    int kk = q >> 2, sub = q & 3;
    int rg = row >> 4, lane = (row & 15) + (sub << 4);
    float4 f0 = ((const float4*)s)[(size_t)i * 2];
    float4 f1 = ((const float4*)s)[(size_t)i * 2 + 1];
    ((bf16x8*)d)[((size_t)rg * KC + kk) * 64 + lane] = pack8(f0, f1);
  }
}

// ---------------- x fp32 -> FM bf16 with optional token gather ----------------
template <int LKC>
__global__ __launch_bounds__(256) void gatherA_kernel(const float* __restrict__ x,
                                                      const int* __restrict__ row_token,
                                                      ushort_t* __restrict__ d,
                                                      int n8, int K) {
  const int KC = 1 << LKC;
  int i = blockIdx.x * 256 + threadIdx.x;
  int stride = gridDim.x * 256;
  for (; i < n8; i += stride) {
    int l  = i & 63;
    int fi = i >> 6;
    int kk = fi & (KC - 1);
    int rg = fi >> LKC;
    int row = rg * 16 + (l & 15);
    int tok = row_token ? row_token[row] : row;
    bf16x8 v = {};
    if (tok >= 0) {
      const float* p = x + (size_t)tok * K + kk * 32 + (l >> 4) * 8;
      v = pack8(*(const float4*)p, *(const float4*)(p + 4));
    }
    ((bf16x8*)d)[i] = v;
  }
}

// ---------------- 1) gate ----------------
__global__ __launch_bounds__(64) void gate_kernel(
    const float* __restrict__ x, const float* __restrict__ gw,
    int* __restrict__ topk_idx, float* __restrict__ topk_w, int* __restrict__ counts)
{
  int t = blockIdx.x;
  int lane = threadIdx.x;
  __shared__ float xs[H_DIM];
  __shared__ float lg[E_NUM];
  const float4* xr = (const float4*)(x + (size_t)t * H_DIM);
  ((float4*)xs)[lane] = xr[lane];
  ((float4*)xs)[lane + 64] = xr[lane + 64];
  __syncthreads();
  if (lane < E_NUM) {
    const float* w = gw + (size_t)lane * H_DIM;
    float acc = 0.f;
    #pragma unroll 8
    for (int h = 0; h < H_DIM; h++) acc += xs[h] * w[h];
    lg[lane] = acc;
  }
  __syncthreads();
  if (lane == 0) {
    float mx = lg[0];
    #pragma unroll
    for (int e = 1; e < E_NUM; e++) mx = fmaxf(mx, lg[e]);
    float sc[E_NUM];
    float sum = 0.f;
    #pragma unroll
    for (int e = 0; e < E_NUM; e++) { sc[e] = expf(lg[e] - mx); sum += sc[e]; }
    float inv = 1.f / sum;
    float m1 = -1.f, m2 = -1.f; int i1 = 0, i2 = 0;
    #pragma unroll
    for (int e = 0; e < E_NUM; e++) {
      float s = sc[e] * inv;
      if (s > m1)      { m2 = m1; i2 = i1; m1 = s; i1 = e; }
      else if (s > m2) { m2 = s; i2 = e; }
    }
    topk_idx[t * 2] = i1; topk_idx[t * 2 + 1] = i2;
    topk_w[t * 2] = m1;  topk_w[t * 2 + 1] = m2;
    atomicAdd(&counts[i1], 1);
    atomicAdd(&counts[i2], 1);
  }
}

// ---------------- 2) padded scan + rowgroup->expert map ----------------
__global__ void offsets_kernel(const int* __restrict__ counts,
                               int* __restrict__ offp, int* __restrict__ cursor,
                               int* __restrict__ rg2e)
{
  if (threadIdx.x == 0) {
    int acc = 0;
    #pragma unroll
    for (int e = 0; e < E_NUM; e++) { offp[e] = acc; acc += (counts[e] + 63) & ~63; }
    offp[E_NUM] = acc;
    for (int r = 0; r < NRG; r++) rg2e[r] = -1;
    for (int e = 0; e < E_NUM; e++) {
      int lo = offp[e] >> 6;
      int hi = (offp[e] + ((counts[e] + 63) & ~63)) >> 6;
      for (int r = lo; r < hi; r++) rg2e[r] = e;
    }
  }
  if (threadIdx.x < E_NUM) cursor[threadIdx.x] = 0;
}

// ---------------- 2b) init padded row arrays ----------------
__global__ __launch_bounds__(256) void initrows_kernel(int* __restrict__ row_token,
                                                       float* __restrict__ row_w) {
  int i = blockIdx.x * 256 + threadIdx.x;
  if (i < RPMAX) { row_token[i] = -1; row_w[i] = 0.f; }
}

// ---------------- 3) scatter ----------------
__global__ __launch_bounds__(256) void scatter_kernel(
    const int* __restrict__ topk_idx, const float* __restrict__ topk_w,
    const int* __restrict__ offp, int* __restrict__ cursor,
    int* __restrict__ row_token, float* __restrict__ row_w)
{
  int t = blockIdx.x * 256 + threadIdx.x;
  if (t >= T_TOK) return;
  #pragma unroll
  for (int k = 0; k < TOPK; k++) {
    int e = topk_idx[t * 2 + k];
    int pos = atomicAdd(&cursor[e], 1);
    int row = offp[e] + pos;
    row_token[row] = t;
    row_w[row] = topk_w[t * 2 + k];
  }
}

// ---------------- 4) fused GU GEMM (routed + shared), uniform tiles ----------
// Tile = 64 rows x 128 cols, 4 waves (each 64x32 of BOTH g and u), 16 kk steps.
// bid < 16*NRG: routed (colb = bid&15, rg = bid>>4, expert = rg2e[rg]).
// else: shared (b2 = bid-16*NRG: colb = b2&7, rgs = b2>>3 in [0,32)).
__global__ __launch_bounds__(256, 4) void gu7_kernel(
    const ushort_t* __restrict__ xgf, const ushort_t* __restrict__ xsf,
    const ushort_t* __restrict__ wgf, const ushort_t* __restrict__ wuf,
    const ushort_t* __restrict__ swgf, const ushort_t* __restrict__ swuf,
    ushort_t* __restrict__ interF, ushort_t* __restrict__ interS,
    const int* __restrict__ rg2e)
{
  const int KC = H_DIM / 32;   // 16
  int bid = blockIdx.x;
  int tid = threadIdx.x, w = tid >> 6, l = tid & 63;
  int fr = l & 15, g = l >> 4;

  const bf16x8 *ap, *bg0, *bg1, *bu0, *bu1;
  bf16x8* op;
  int rg0, kkg, KCd;

  if (bid < 16 * NRG) {
    int colb = bid & 15, rg = bid >> 4;
    int e = rg2e[rg]; if (e < 0) return;
    rg0 = rg * 4;
    ap = (const bf16x8*)xgf + (size_t)rg0 * KC * 64 + l;
    size_t cg = (size_t)(e * (I_DIM >> 4) + colb * 8 + w * 2) * KC * 64 + l;
    bg0 = (const bf16x8*)wgf + cg;  bg1 = bg0 + (size_t)KC * 64;
    bu0 = (const bf16x8*)wuf + cg;  bu1 = bu0 + (size_t)KC * 64;
    KCd = I_DIM >> 5; kkg = colb * 4 + w;
    op = (bf16x8*)interF;
  } else {
    int b2 = bid - 16 * NRG;
    int colb = b2 & 7, rgs = b2 >> 3;
    rg0 = rgs * 4;
    ap = (const bf16x8*)xsf + (size_t)rg0 * KC * 64 + l;
    size_t cg = (size_t)(colb * 8 + w * 2) * KC * 64 + l;
    bg0 = (const bf16x8*)swgf + cg; bg1 = bg0 + (size_t)KC * 64;
    bu0 = (const bf16x8*)swuf + cg; bu1 = bu0 + (size_t)KC * 64;
    KCd = IS_DIM >> 5; kkg = colb * 4 + w;
    op = (bf16x8*)interS;
  }

  __shared__ ushort_t lds[4][64][40];

  f32x4 accg[4][2] = {}, accu[4][2] = {};
  #pragma unroll 4
  for (int kk = 0; kk < KC; kk++) {
    bf16x8 a[4], bgv[2], buv[2];
    #pragma unroll
    for (int mi = 0; mi < 4; mi++) a[mi] = ap[((size_t)mi * KC + kk) * 64];
    bgv[0] = bg0[(size_t)kk * 64]; bgv[1] = bg1[(size_t)kk * 64];
    buv[0] = bu0[(size_t)kk * 64]; buv[1] = bu1[(size_t)kk * 64];
    #pragma unroll
    for (int mi = 0; mi < 4; mi++) {
      accg[mi][0] = __builtin_amdgcn_mfma_f32_16x16x32_bf16(a[mi], bgv[0], accg[mi][0], 0, 0, 0);
      accg[mi][1] = __builtin_amdgcn_mfma_f32_16x16x32_bf16(a[mi], bgv[1], accg[mi][1], 0, 0, 0);
      accu[mi][0] = __builtin_amdgcn_mfma_f32_16x16x32_bf16(a[mi], buv[0], accu[mi][0], 0, 0, 0);
      accu[mi][1] = __builtin_amdgcn_mfma_f32_16x16x32_bf16(a[mi], buv[1], accu[mi][1], 0, 0, 0);
    }
  }

  // silu(g)*u -> intra-wave LDS bounce -> FM write (contiguous 1KB per wave)
  #pragma unroll
  for (int mi = 0; mi < 4; mi++)
    #pragma unroll
    for (int c = 0; c < 2; c++)
      #pragma unroll
      for (int j = 0; j < 4; j++) {
        float gg = accg[mi][c][j], uu = accu[mi][c][j];
        float s = (gg / (1.f + expf(-gg))) * uu;
        lds[w][mi * 16 + g * 4 + j][c * 16 + fr] = f2bf(s);
      }
  #pragma unroll
  for (int rgi = 0; rgi < 4; rgi++) {
    bf16x8 v = *(const bf16x8*)&lds[w][rgi * 16 + fr][g * 8];
    op[((size_t)(rg0 + rgi) * KCd + kkg) * 64 + l] = v;
  }
}

// ---------------- 5) fused down GEMM (routed splitK4 + shared splitK2) -------
// Uniform tile: 64 rows x 128 cols x 16 kk. All paths atomicAdd into out (=0).
// bid < 16*NRG: routed: kc=bid&3, colb=(bid>>2)&3, rg=bid>>4.
// else b2: kc=b2&1, colb=(b2>>1)&3, rgs=b2>>3 in [0,32).
__global__ __launch_bounds__(256, 4) void down7_kernel(
    const ushort_t* __restrict__ interF, const ushort_t* __restrict__ interS,
    const ushort_t* __restrict__ wdf, const ushort_t* __restrict__ swdf,
    float* __restrict__ outp,
    const int* __restrict__ row_token, const float* __restrict__ row_w,
    const int* __restrict__ rg2e)
{
  int bid = blockIdx.x;
  int tid = threadIdx.x, w = tid >> 6, l = tid & 63;
  int fr = l & 15, g = l >> 4;

  const bf16x8 *ap, *b0, *b1;
  int colb, rowbase;
  bool routed;

  if (bid < 16 * NRG) {
    int kc = bid & 3; colb = (bid >> 2) & 3; int rg = bid >> 4;
    int e = rg2e[rg]; if (e < 0) return;
    routed = true; rowbase = rg * 64;
    const int KCd = I_DIM >> 5;   // 64
    int kk0 = kc * 16;
    ap = (const bf16x8*)interF + ((size_t)(rg * 4) * KCd + kk0) * 64 + l;
    size_t cg = ((size_t)(e * (H_DIM >> 4) + colb * 8 + w * 2) * KCd + kk0) * 64 + l;
    b0 = (const bf16x8*)wdf + cg; b1 = b0 + (size_t)KCd * 64;
    // strides via KCd captured below
    f32x4 acc[4][2] = {};
    #pragma unroll 4
    for (int kk = 0; kk < 16; kk++) {
      bf16x8 a[4], bv[2];
      #pragma unroll
      for (int mi = 0; mi < 4; mi++) a[mi] = ap[((size_t)mi * KCd + kk) * 64];
      bv[0] = b0[(size_t)kk * 64]; bv[1] = b1[(size_t)kk * 64];
      #pragma unroll
      for (int mi = 0; mi < 4; mi++) {
        acc[mi][0] = __builtin_amdgcn_mfma_f32_16x16x32_bf16(a[mi], bv[0], acc[mi][0], 0, 0, 0);
        acc[mi][1] = __builtin_amdgcn_mfma_f32_16x16x32_bf16(a[mi], bv[1], acc[mi][1], 0, 0, 0);
      }
    }
    int c0 = colb * 128 + w * 32;
    #pragma unroll
    for (int mi = 0; mi < 4; mi++)
      #pragma unroll
      for (int j = 0; j < 4; j++) {
        int grow = rowbase + mi * 16 + g * 4 + j;
        int tk = row_token[grow];
        if (tk >= 0) {
          float rw = row_w[grow];
          atomicAdd(&outp[(size_t)tk * H_DIM + c0 + fr],      acc[mi][0][j] * rw);
          atomicAdd(&outp[(size_t)tk * H_DIM + c0 + 16 + fr], acc[mi][1][j] * rw);
        }
      }
  } else {
    int b2 = bid - 16 * NRG;
    int kc = b2 & 1; colb = (b2 >> 1) & 3; int rgs = b2 >> 3;
    rowbase = rgs * 64;
    const int KCd = IS_DIM >> 5;  // 32
    int kk0 = kc * 16;
    ap = (const bf16x8*)interS + ((size_t)(rgs * 4) * KCd + kk0) * 64 + l;
    size_t cg = ((size_t)(colb * 8 + w * 2) * KCd + kk0) * 64 + l;
    b0 = (const bf16x8*)swdf + cg; b1 = b0 + (size_t)KCd * 64;
    f32x4 acc[4][2] = {};
    #pragma unroll 4
    for (int kk = 0; kk < 16; kk++) {
      bf16x8 a[4], bv[2];
      #pragma unroll
      for (int mi = 0; mi < 4; mi++) a[mi] = ap[((size_t)mi * KCd + kk) * 64];
      bv[0] = b0[(size_t)kk * 64]; bv[1] = b1[(size_t)kk * 64];
      #pragma unroll
      for (int mi = 0; mi < 4; mi++) {
        acc[mi][0] = __builtin_amdgcn_mfma_f32_16x16x32_bf16(a[mi], bv[0], acc[mi][0], 0, 0, 0);
        acc[mi][1] = __builtin_amdgcn_mfma_f32_16x16x32_bf16(a[mi], bv[1], acc[mi][1], 0, 0, 0);
      }
    }
    int c0 = colb * 128 + w * 32;
    #pragma unroll
    for (int mi = 0; mi < 4; mi++)
      #pragma unroll
      for (int j = 0; j < 4; j++) {
        int n = rowbase + mi * 16 + g * 4 + j;
        atomicAdd(&outp[(size_t)n * H_DIM + c0 + fr],      acc[mi][0][j]);
        atomicAdd(&outp[(size_t)n * H_DIM + c0 + 16 + fr], acc[mi][1][j]);
      }
  }
}

// ---------------- launch ----------------
extern "C" void kernel_launch(void* const* d_in, const int* in_sizes, int n_in,
                              void* d_out, int out_size, void* d_ws, size_t ws_size,
                              hipStream_t stream) {
  const float* x       = (const float*)d_in[0];
  const float* gate_w  = (const float*)d_in[1];
  const float* w_gate  = (const float*)d_in[2];
  const float* w_up    = (const float*)d_in[3];
  const float* w_down  = (const float*)d_in[4];
  const float* sw_gate = (const float*)d_in[5];
  const float* sw_up   = (const float*)d_in[6];
  const float* sw_down = (const float*)d_in[7];
  float* out = (float*)d_out;

  char* ws = (char*)d_ws;
  int*   counts    = (int*)ws;                      // 16
  int*   cursor    = (int*)(ws + 64);               // 16
  int*   offp      = (int*)(ws + 128);              // 17
  int*   rg2e      = (int*)(ws + 256);              // 80
  int*   topk_idx  = (int*)(ws + 640);              // 4096
  float* topk_w    = (float*)(ws + 17024);          // 4096
  int*   row_token = (int*)(ws + 33408);            // RPMAX
  float* row_w     = (float*)(ws + 33408 + RPMAX * 4);
  size_t off = 33408 + (size_t)RPMAX * 8;
  off = (off + 255) & ~(size_t)255;
  ushort_t* xgf  = (ushort_t*)(ws + off); off += (size_t)RPMAX * H_DIM * 2;         // 5 MiB
  ushort_t* xsf  = (ushort_t*)(ws + off); off += (size_t)T_TOK * H_DIM * 2;         // 2 MiB
  ushort_t* wgf  = (ushort_t*)(ws + off); off += (size_t)E_NUM * I_DIM * H_DIM * 2; // 32 MiB
  ushort_t* wuf  = (ushort_t*)(ws + off); off += (size_t)E_NUM * I_DIM * H_DIM * 2; // 32 MiB
  ushort_t* wdf  = (ushort_t*)(ws + off); off += (size_t)E_NUM * H_DIM * I_DIM * 2; // 32 MiB
  ushort_t* swgf = (ushort_t*)(ws + off); off += (size_t)IS_DIM * H_DIM * 2;        // 1 MiB
  ushort_t* swuf = (ushort_t*)(ws + off); off += (size_t)IS_DIM * H_DIM * 2;        // 1 MiB
  ushort_t* swdf = (ushort_t*)(ws + off); off += (size_t)H_DIM * IS_DIM * 2;        // 1 MiB
  ushort_t* interF = (ushort_t*)(ws + off); off += (size_t)RPMAX * I_DIM * 2;       // 20 MiB
  ushort_t* interS = (ushort_t*)(ws + off); off += (size_t)T_TOK * IS_DIM * 2;      // 4 MiB

  hipMemsetAsync(counts, 0, 64, stream);
  hipMemsetAsync(out, 0, (size_t)out_size * 4, stream);
  gate_kernel<<<T_TOK, 64, 0, stream>>>(x, gate_w, topk_idx, topk_w, counts);
  offsets_kernel<<<1, 64, 0, stream>>>(counts, offp, cursor, rg2e);
  initrows_kernel<<<RPMAX / 256, 256, 0, stream>>>(row_token, row_w);
  scatter_kernel<<<(T_TOK + 255) / 256, 256, 0, stream>>>(topk_idx, topk_w, offp, cursor,
                                                          row_token, row_w);
  // A-operands into FM bf16
  gatherA_kernel<4><<<640, 256, 0, stream>>>(x, row_token, xgf, RPMAX * H_DIM / 8, H_DIM);
  gatherA_kernel<4><<<512, 256, 0, stream>>>(x, nullptr, xsf, T_TOK * H_DIM / 8, H_DIM);
  // weights into FM bf16 (coalesced-read permute)
  permw_kernel<4><<<4096, 256, 0, stream>>>(w_gate, wgf, E_NUM * I_DIM * H_DIM / 8);
  permw_kernel<4><<<4096, 256, 0, stream>>>(w_up,   wuf, E_NUM * I_DIM * H_DIM / 8);
  permw_kernel<6><<<4096, 256, 0, stream>>>(w_down, wdf, E_NUM * H_DIM * I_DIM / 8);
  permw_kernel<4><<<256, 256, 0, stream>>>(sw_gate, swgf, IS_DIM * H_DIM / 8);
  permw_kernel<4><<<256, 256, 0, stream>>>(sw_up,   swuf, IS_DIM * H_DIM / 8);
  permw_kernel<5><<<256, 256, 0, stream>>>(sw_down, swdf, H_DIM * IS_DIM / 8);

  // fused GU: routed tiles (16 colb x 80 rg = 1280) + shared (8 x 32 = 256)
  gu7_kernel<<<16 * NRG + 8 * 32, 256, 0, stream>>>(
      xgf, xsf, wgf, wuf, swgf, swuf, interF, interS, rg2e);
  // fused down: routed (4 colb x 4 kc x 80 rg = 1280) + shared (4 x 2 x 32 = 256)
  down7_kernel<<<16 * NRG + 8 * 32, 256, 0, stream>>>(
      interF, interS, wdf, swdf, out, row_token, row_w, rg2e);
}

// Round 8
// 329.058 us; speedup vs baseline: 1.0001x; 1.0001x over previous
//
#include <hip/hip_runtime.h>
#include <hip/hip_bf16.h>
#include <math.h>

// ---------------- problem constants ----------------
#define T_TOK 2048
#define H_DIM 512
#define E_NUM 16
#define TOPK  2
#define I_DIM 2048
#define IS_DIM 1024
#define NROWS (T_TOK * TOPK)
#define RPMAX 5120             // padded grouped rows upper bound
#define NRG   (RPMAX / 64)     // 80 rowgroups

typedef __attribute__((ext_vector_type(8))) short bf16x8;
typedef __attribute__((ext_vector_type(4))) float f32x4;
typedef unsigned short ushort_t;

static __device__ __forceinline__ unsigned short f2bf(float f) {
  unsigned int u = __float_as_uint(f);
  unsigned int r = (u + 0x7fffu + ((u >> 16) & 1u)) >> 16;   // RNE
  return (unsigned short)r;
}

static __device__ __forceinline__ bf16x8 pack8(float4 a, float4 b) {
  bf16x8 v;
  v[0] = (short)f2bf(a.x); v[1] = (short)f2bf(a.y);
  v[2] = (short)f2bf(a.z); v[3] = (short)f2bf(a.w);
  v[4] = (short)f2bf(b.x); v[5] = (short)f2bf(b.y);
  v[6] = (short)f2bf(b.z); v[7] = (short)f2bf(b.w);
  return v;
}

// ================= fragment-major (FM) layout =================
// M[R][K] row-major -> chunk c = rg*(K/32) + kk; lane l holds
// M[rg*16 + (l&15)][kk*32 + (l>>4)*8 .. +8] (one bf16x8, 16B).
// A wave reading one chunk = ONE contiguous 1KB load.

// ---------------- weights fp32 row-major -> FM bf16 (coalesced reads) --------
template <int LKC>
__global__ __launch_bounds__(256) void permw_kernel(const float* __restrict__ s,
                                                    ushort_t* __restrict__ d, int n8) {
  const int KC = 1 << LKC;
  const int LQ = LKC + 2;             // 8-elem units per row = 4*KC
  int i = blockIdx.x * 256 + threadIdx.x;
  int stride = gridDim.x * 256;
  for (; i < n8; i += stride) {
    int row = i >> LQ;
    int q   = i & ((1 << LQ) - 1);
    int kk = q >> 2, sub = q & 3;
    int rg = row >> 4, lane = (row & 15) + (sub << 4);
    float4 f0 = ((const float4*)s)[(size_t)i * 2];
    float4 f1 = ((const float4*)s)[(size_t)i * 2 + 1];
    ((bf16x8*)d)[((size_t)rg * KC + kk) * 64 + lane] = pack8(f0, f1);
  }
}

// ---------------- x fp32 -> FM bf16 with optional token gather ----------------
template <int LKC>
__global__ __launch_bounds__(256) void gatherA_kernel(const float* __restrict__ x,
                                                      const int* __restrict__ row_token,
                                                      ushort_t* __restrict__ d,
                                                      int n8, int K) {
  const int KC = 1 << LKC;
  int i = blockIdx.x * 256 + threadIdx.x;
  int stride = gridDim.x * 256;
  for (; i < n8; i += stride) {
    int l  = i & 63;
    int fi = i >> 6;
    int kk = fi & (KC - 1);
    int rg = fi >> LKC;
    int row = rg * 16 + (l & 15);
    int tok = row_token ? row_token[row] : row;
    bf16x8 v = {};
    if (tok >= 0) {
      const float* p = x + (size_t)tok * K + kk * 32 + (l >> 4) * 8;
      v = pack8(*(const float4*)p, *(const float4*)(p + 4));
    }
    ((bf16x8*)d)[i] = v;
  }
}

// ---------------- 1) gate ----------------
__global__ __launch_bounds__(64) void gate_kernel(
    const float* __restrict__ x, const float* __restrict__ gw,
    int* __restrict__ topk_idx, float* __restrict__ topk_w, int* __restrict__ counts)
{
  int t = blockIdx.x;
  int lane = threadIdx.x;
  __shared__ float xs[H_DIM];
  __shared__ float lg[E_NUM];
  const float4* xr = (const float4*)(x + (size_t)t * H_DIM);
  ((float4*)xs)[lane] = xr[lane];
  ((float4*)xs)[lane + 64] = xr[lane + 64];
  __syncthreads();
  if (lane < E_NUM) {
    const float* w = gw + (size_t)lane * H_DIM;
    float acc = 0.f;
    #pragma unroll 8
    for (int h = 0; h < H_DIM; h++) acc += xs[h] * w[h];
    lg[lane] = acc;
  }
  __syncthreads();
  if (lane == 0) {
    float mx = lg[0];
    #pragma unroll
    for (int e = 1; e < E_NUM; e++) mx = fmaxf(mx, lg[e]);
    float sc[E_NUM];
    float sum = 0.f;
    #pragma unroll
    for (int e = 0; e < E_NUM; e++) { sc[e] = expf(lg[e] - mx); sum += sc[e]; }
    float inv = 1.f / sum;
    float m1 = -1.f, m2 = -1.f; int i1 = 0, i2 = 0;
    #pragma unroll
    for (int e = 0; e < E_NUM; e++) {
      float s = sc[e] * inv;
      if (s > m1)      { m2 = m1; i2 = i1; m1 = s; i1 = e; }
      else if (s > m2) { m2 = s; i2 = e; }
    }
    topk_idx[t * 2] = i1; topk_idx[t * 2 + 1] = i2;
    topk_w[t * 2] = m1;  topk_w[t * 2 + 1] = m2;
    atomicAdd(&counts[i1], 1);
    atomicAdd(&counts[i2], 1);
  }
}

// ---------------- 2) padded scan + rowgroup->expert map ----------------
__global__ void offsets_kernel(const int* __restrict__ counts,
                               int* __restrict__ offp, int* __restrict__ cursor,
                               int* __restrict__ rg2e)
{
  if (threadIdx.x == 0) {
    int acc = 0;
    #pragma unroll
    for (int e = 0; e < E_NUM; e++) { offp[e] = acc; acc += (counts[e] + 63) & ~63; }
    offp[E_NUM] = acc;
    for (int r = 0; r < NRG; r++) rg2e[r] = -1;
    for (int e = 0; e < E_NUM; e++) {
      int lo = offp[e] >> 6;
      int hi = (offp[e] + ((counts[e] + 63) & ~63)) >> 6;
      for (int r = lo; r < hi; r++) rg2e[r] = e;
    }
  }
  if (threadIdx.x < E_NUM) cursor[threadIdx.x] = 0;
}

// ---------------- 2b) init padded row arrays ----------------
__global__ __launch_bounds__(256) void initrows_kernel(int* __restrict__ row_token,
                                                       float* __restrict__ row_w) {
  int i = blockIdx.x * 256 + threadIdx.x;
  if (i < RPMAX) { row_token[i] = -1; row_w[i] = 0.f; }
}

// ---------------- 3) scatter ----------------
__global__ __launch_bounds__(256) void scatter_kernel(
    const int* __restrict__ topk_idx, const float* __restrict__ topk_w,
    const int* __restrict__ offp, int* __restrict__ cursor,
    int* __restrict__ row_token, float* __restrict__ row_w)
{
  int t = blockIdx.x * 256 + threadIdx.x;
  if (t >= T_TOK) return;
  #pragma unroll
  for (int k = 0; k < TOPK; k++) {
    int e = topk_idx[t * 2 + k];
    int pos = atomicAdd(&cursor[e], 1);
    int row = offp[e] + pos;
    row_token[row] = t;
    row_w[row] = topk_w[t * 2 + k];
  }
}

// ---------------- 4) fused GU GEMM, uniform tiles, REG double-buffered -------
// Tile = 64 rows x 128 cols, 4 waves (each 64x32 of BOTH g and u), KC=16 kk.
__global__ __launch_bounds__(256, 2) void gu8_kernel(
    const ushort_t* __restrict__ xgf, const ushort_t* __restrict__ xsf,
    const ushort_t* __restrict__ wgf, const ushort_t* __restrict__ wuf,
    const ushort_t* __restrict__ swgf, const ushort_t* __restrict__ swuf,
    ushort_t* __restrict__ interF, ushort_t* __restrict__ interS,
    const int* __restrict__ rg2e)
{
  const int KC = H_DIM / 32;   // 16
  int bid = blockIdx.x;
  int tid = threadIdx.x, w = tid >> 6, l = tid & 63;
  int fr = l & 15, g = l >> 4;

  const bf16x8 *ap, *bgp0, *bgp1, *bup0, *bup1;
  bf16x8* op;
  int rg0, kkg, KCd;

  if (bid < 16 * NRG) {
    int colb = bid & 15, rg = bid >> 4;
    int e = rg2e[rg]; if (e < 0) return;
    rg0 = rg * 4;
    ap = (const bf16x8*)xgf + (size_t)rg0 * KC * 64 + l;
    size_t cg = (size_t)(e * (I_DIM >> 4) + colb * 8 + w * 2) * KC * 64 + l;
    bgp0 = (const bf16x8*)wgf + cg;  bgp1 = bgp0 + (size_t)KC * 64;
    bup0 = (const bf16x8*)wuf + cg;  bup1 = bup0 + (size_t)KC * 64;
    KCd = I_DIM >> 5; kkg = colb * 4 + w;
    op = (bf16x8*)interF;
  } else {
    int b2 = bid - 16 * NRG;
    int colb = b2 & 7, rgs = b2 >> 3;
    rg0 = rgs * 4;
    ap = (const bf16x8*)xsf + (size_t)rg0 * KC * 64 + l;
    size_t cg = (size_t)(colb * 8 + w * 2) * KC * 64 + l;
    bgp0 = (const bf16x8*)swgf + cg; bgp1 = bgp0 + (size_t)KC * 64;
    bup0 = (const bf16x8*)swuf + cg; bup1 = bup0 + (size_t)KC * 64;
    KCd = IS_DIM >> 5; kkg = colb * 4 + w;
    op = (bf16x8*)interS;
  }

  __shared__ ushort_t lds[4][64][40];

  f32x4 accg[4][2] = {}, accu[4][2] = {};
  bf16x8 a0[4], g0v[2], u0v[2];   // staging set 0 (even kk)
  bf16x8 a1[4], g1v[2], u1v[2];   // staging set 1 (odd kk)

  auto load0 = [&](int kk) {
    #pragma unroll
    for (int mi = 0; mi < 4; mi++) a0[mi] = ap[((size_t)mi * KC + kk) * 64];
    g0v[0] = bgp0[(size_t)kk * 64]; g0v[1] = bgp1[(size_t)kk * 64];
    u0v[0] = bup0[(size_t)kk * 64]; u0v[1] = bup1[(size_t)kk * 64];
  };
  auto load1 = [&](int kk) {
    #pragma unroll
    for (int mi = 0; mi < 4; mi++) a1[mi] = ap[((size_t)mi * KC + kk) * 64];
    g1v[0] = bgp0[(size_t)kk * 64]; g1v[1] = bgp1[(size_t)kk * 64];
    u1v[0] = bup0[(size_t)kk * 64]; u1v[1] = bup1[(size_t)kk * 64];
  };
  auto mfma0 = [&]() {
    #pragma unroll
    for (int mi = 0; mi < 4; mi++) {
      accg[mi][0] = __builtin_amdgcn_mfma_f32_16x16x32_bf16(a0[mi], g0v[0], accg[mi][0], 0, 0, 0);
      accg[mi][1] = __builtin_amdgcn_mfma_f32_16x16x32_bf16(a0[mi], g0v[1], accg[mi][1], 0, 0, 0);
      accu[mi][0] = __builtin_amdgcn_mfma_f32_16x16x32_bf16(a0[mi], u0v[0], accu[mi][0], 0, 0, 0);
      accu[mi][1] = __builtin_amdgcn_mfma_f32_16x16x32_bf16(a0[mi], u0v[1], accu[mi][1], 0, 0, 0);
    }
  };
  auto mfma1 = [&]() {
    #pragma unroll
    for (int mi = 0; mi < 4; mi++) {
      accg[mi][0] = __builtin_amdgcn_mfma_f32_16x16x32_bf16(a1[mi], g1v[0], accg[mi][0], 0, 0, 0);
      accg[mi][1] = __builtin_amdgcn_mfma_f32_16x16x32_bf16(a1[mi], g1v[1], accg[mi][1], 0, 0, 0);
      accu[mi][0] = __builtin_amdgcn_mfma_f32_16x16x32_bf16(a1[mi], u1v[0], accu[mi][0], 0, 0, 0);
      accu[mi][1] = __builtin_amdgcn_mfma_f32_16x16x32_bf16(a1[mi], u1v[1], accu[mi][1], 0, 0, 0);
    }
  };

  load0(0);
  #pragma unroll
  for (int kk = 0; kk < KC; kk += 2) {
    load1(kk + 1);
    mfma0();
    if (kk + 2 < KC) load0(kk + 2);
    mfma1();
  }

  // silu(g)*u -> intra-wave LDS bounce -> FM write (contiguous 1KB per wave)
  #pragma unroll
  for (int mi = 0; mi < 4; mi++)
    #pragma unroll
    for (int c = 0; c < 2; c++)
      #pragma unroll
      for (int j = 0; j < 4; j++) {
        float gg = accg[mi][c][j], uu = accu[mi][c][j];
        float s = (gg / (1.f + expf(-gg))) * uu;
        lds[w][mi * 16 + g * 4 + j][c * 16 + fr] = f2bf(s);
      }
  #pragma unroll
  for (int rgi = 0; rgi < 4; rgi++) {
    bf16x8 v = *(const bf16x8*)&lds[w][rgi * 16 + fr][g * 8];
    op[((size_t)(rg0 + rgi) * KCd + kkg) * 64 + l] = v;
  }
}

// ---------------- 5) down GEMM, uniform tiles, REG double-buffered ----------
// Tile = 64 rows x 128 cols x 32 kk. Routed: splitK2 + weighted atomics.
// Shared: full K (KCd=32), plain stores (initializes out; runs first).
__global__ __launch_bounds__(256, 4) void down8_kernel(
    const ushort_t* __restrict__ Af, const ushort_t* __restrict__ Bf,
    float* __restrict__ outp,
    const int* __restrict__ row_token,      // null -> identity (shared)
    const float* __restrict__ row_w,        // null -> store path
    const int* __restrict__ rg2e,           // null -> shared (e=0)
    int KCd, int NKC)
{
  int bid = blockIdx.x;
  int kc, colb, rg;
  if (NKC == 2) { kc = bid & 1; colb = (bid >> 1) & 3; rg = bid >> 3; }
  else          { kc = 0;       colb = bid & 3;        rg = bid >> 2; }
  int e = 0;
  if (rg2e) { e = rg2e[rg]; if (e < 0) return; }

  int tid = threadIdx.x, w = tid >> 6, l = tid & 63;
  int fr = l & 15, g = l >> 4;
  int kk0 = kc * 32;

  const bf16x8* ap = (const bf16x8*)Af + ((size_t)(rg * 4) * KCd + kk0) * 64 + l;
  size_t cg = ((size_t)(e * (H_DIM >> 4) + colb * 8 + w * 2) * KCd + kk0) * 64 + l;
  const bf16x8* b0p = (const bf16x8*)Bf + cg;
  const bf16x8* b1p = b0p + (size_t)KCd * 64;

  f32x4 acc[4][2] = {};
  bf16x8 a0[4], b0v[2];
  bf16x8 a1[4], b1v[2];

  auto load0 = [&](int kk) {
    #pragma unroll
    for (int mi = 0; mi < 4; mi++) a0[mi] = ap[((size_t)mi * KCd + kk) * 64];
    b0v[0] = b0p[(size_t)kk * 64]; b0v[1] = b1p[(size_t)kk * 64];
  };
  auto load1 = [&](int kk) {
    #pragma unroll
    for (int mi = 0; mi < 4; mi++) a1[mi] = ap[((size_t)mi * KCd + kk) * 64];
    b1v[0] = b0p[(size_t)kk * 64]; b1v[1] = b1p[(size_t)kk * 64];
  };
  auto mfma0 = [&]() {
    #pragma unroll
    for (int mi = 0; mi < 4; mi++) {
      acc[mi][0] = __builtin_amdgcn_mfma_f32_16x16x32_bf16(a0[mi], b0v[0], acc[mi][0], 0, 0, 0);
      acc[mi][1] = __builtin_amdgcn_mfma_f32_16x16x32_bf16(a0[mi], b0v[1], acc[mi][1], 0, 0, 0);
    }
  };
  auto mfma1 = [&]() {
    #pragma unroll
    for (int mi = 0; mi < 4; mi++) {
      acc[mi][0] = __builtin_amdgcn_mfma_f32_16x16x32_bf16(a1[mi], b1v[0], acc[mi][0], 0, 0, 0);
      acc[mi][1] = __builtin_amdgcn_mfma_f32_16x16x32_bf16(a1[mi], b1v[1], acc[mi][1], 0, 0, 0);
    }
  };

  load0(0);
  #pragma unroll
  for (int kk = 0; kk < 32; kk += 2) {
    load1(kk + 1);
    mfma0();
    if (kk + 2 < 32) load0(kk + 2);
    mfma1();
  }

  int c0 = colb * 128 + w * 32;
  int rowbase = rg * 64;
  #pragma unroll
  for (int mi = 0; mi < 4; mi++)
    #pragma unroll
    for (int j = 0; j < 4; j++) {
      int grow = rowbase + mi * 16 + g * 4 + j;
      if (row_w) {
        int tk = row_token[grow];
        if (tk >= 0) {
          float rw = row_w[grow];
          atomicAdd(&outp[(size_t)tk * H_DIM + c0 + fr],      acc[mi][0][j] * rw);
          atomicAdd(&outp[(size_t)tk * H_DIM + c0 + 16 + fr], acc[mi][1][j] * rw);
        }
      } else {
        outp[(size_t)grow * H_DIM + c0 + fr]      = acc[mi][0][j];
        outp[(size_t)grow * H_DIM + c0 + 16 + fr] = acc[mi][1][j];
      }
    }
}

// ---------------- launch ----------------
extern "C" void kernel_launch(void* const* d_in, const int* in_sizes, int n_in,
                              void* d_out, int out_size, void* d_ws, size_t ws_size,
                              hipStream_t stream) {
  const float* x       = (const float*)d_in[0];
  const float* gate_w  = (const float*)d_in[1];
  const float* w_gate  = (const float*)d_in[2];
  const float* w_up    = (const float*)d_in[3];
  const float* w_down  = (const float*)d_in[4];
  const float* sw_gate = (const float*)d_in[5];
  const float* sw_up   = (const float*)d_in[6];
  const float* sw_down = (const float*)d_in[7];
  float* out = (float*)d_out;

  char* ws = (char*)d_ws;
  int*   counts    = (int*)ws;                      // 16
  int*   cursor    = (int*)(ws + 64);               // 16
  int*   offp      = (int*)(ws + 128);              // 17
  int*   rg2e      = (int*)(ws + 256);              // 80
  int*   topk_idx  = (int*)(ws + 640);              // 4096
  float* topk_w    = (float*)(ws + 17024);          // 4096
  int*   row_token = (int*)(ws + 33408);            // RPMAX
  float* row_w     = (float*)(ws + 33408 + RPMAX * 4);
  size_t off = 33408 + (size_t)RPMAX * 8;
  off = (off + 255) & ~(size_t)255;
  ushort_t* xgf  = (ushort_t*)(ws + off); off += (size_t)RPMAX * H_DIM * 2;         // 5 MiB
  ushort_t* xsf  = (ushort_t*)(ws + off); off += (size_t)T_TOK * H_DIM * 2;         // 2 MiB
  ushort_t* wgf  = (ushort_t*)(ws + off); off += (size_t)E_NUM * I_DIM * H_DIM * 2; // 32 MiB
  ushort_t* wuf  = (ushort_t*)(ws + off); off += (size_t)E_NUM * I_DIM * H_DIM * 2; // 32 MiB
  ushort_t* wdf  = (ushort_t*)(ws + off); off += (size_t)E_NUM * H_DIM * I_DIM * 2; // 32 MiB
  ushort_t* swgf = (ushort_t*)(ws + off); off += (size_t)IS_DIM * H_DIM * 2;        // 1 MiB
  ushort_t* swuf = (ushort_t*)(ws + off); off += (size_t)IS_DIM * H_DIM * 2;        // 1 MiB
  ushort_t* swdf = (ushort_t*)(ws + off); off += (size_t)H_DIM * IS_DIM * 2;        // 1 MiB
  ushort_t* interF = (ushort_t*)(ws + off); off += (size_t)RPMAX * I_DIM * 2;       // 20 MiB
  ushort_t* interS = (ushort_t*)(ws + off); off += (size_t)T_TOK * IS_DIM * 2;      // 4 MiB

  hipMemsetAsync(counts, 0, 64, stream);
  gate_kernel<<<T_TOK, 64, 0, stream>>>(x, gate_w, topk_idx, topk_w, counts);
  offsets_kernel<<<1, 64, 0, stream>>>(counts, offp, cursor, rg2e);
  initrows_kernel<<<RPMAX / 256, 256, 0, stream>>>(row_token, row_w);
  scatter_kernel<<<(T_TOK + 255) / 256, 256, 0, stream>>>(topk_idx, topk_w, offp, cursor,
                                                          row_token, row_w);
  // A-operands into FM bf16
  gatherA_kernel<4><<<640, 256, 0, stream>>>(x, row_token, xgf, RPMAX * H_DIM / 8, H_DIM);
  gatherA_kernel<4><<<512, 256, 0, stream>>>(x, nullptr, xsf, T_TOK * H_DIM / 8, H_DIM);
  // weights into FM bf16 (coalesced-read permute)
  permw_kernel<4><<<4096, 256, 0, stream>>>(w_gate, wgf, E_NUM * I_DIM * H_DIM / 8);
  permw_kernel<4><<<4096, 256, 0, stream>>>(w_up,   wuf, E_NUM * I_DIM * H_DIM / 8);
  permw_kernel<6><<<4096, 256, 0, stream>>>(w_down, wdf, E_NUM * H_DIM * I_DIM / 8);
  permw_kernel<4><<<256, 256, 0, stream>>>(sw_gate, swgf, IS_DIM * H_DIM / 8);
  permw_kernel<4><<<256, 256, 0, stream>>>(sw_up,   swuf, IS_DIM * H_DIM / 8);
  permw_kernel<5><<<256, 256, 0, stream>>>(sw_down, swdf, H_DIM * IS_DIM / 8);

  // fused GU: routed (16 colb x 80 rg = 1280) + shared (8 colb x 32 = 256)
  gu8_kernel<<<16 * NRG + 8 * 32, 256, 0, stream>>>(
      xgf, xsf, wgf, wuf, swgf, swuf, interF, interS, rg2e);
  // shared down FIRST (plain stores initialize out): 4 colb x 32 rg = 128 blocks
  down8_kernel<<<4 * 32, 256, 0, stream>>>(
      interS, swdf, out, nullptr, nullptr, nullptr, IS_DIM >> 5, 1);
  // routed down: splitK2 atomics: 2 kc x 4 colb x 80 rg = 640 blocks
  down8_kernel<<<8 * NRG, 256, 0, stream>>>(
      interF, wdf, out, row_token, row_w, rg2e, I_DIM >> 5, 2);
}

// Round 9
// 286.248 us; speedup vs baseline: 1.1497x; 1.1496x over previous
//
#include <hip/hip_runtime.h>
#include <hip/hip_bf16.h>
#include <math.h>

// ---------------- problem constants ----------------
#define T_TOK 2048
#define H_DIM 512
#define E_NUM 16
#define TOPK  2
#define I_DIM 2048
#define IS_DIM 1024
#define RPMAX 6144             // padded grouped rows (128-aligned per expert)
#define NRT128 (RPMAX / 128)   // 48
#define NRT64  (RPMAX / 64)    // 96

typedef __attribute__((ext_vector_type(8))) short bf16x8;
typedef __attribute__((ext_vector_type(4))) float f32x4;
typedef unsigned short ushort_t;

static __device__ __forceinline__ unsigned short f2bf(float f) {
  unsigned int u = __float_as_uint(f);
  unsigned int r = (u + 0x7fffu + ((u >> 16) & 1u)) >> 16;   // RNE
  return (unsigned short)r;
}

static __device__ __forceinline__ bf16x8 pack8(float4 a, float4 b) {
  bf16x8 v;
  v[0] = (short)f2bf(a.x); v[1] = (short)f2bf(a.y);
  v[2] = (short)f2bf(a.z); v[3] = (short)f2bf(a.w);
  v[4] = (short)f2bf(b.x); v[5] = (short)f2bf(b.y);
  v[6] = (short)f2bf(b.z); v[7] = (short)f2bf(b.w);
  return v;
}

// async global->LDS, 16B/lane: global src per-lane, LDS dst wave-uniform+lane*16
static __device__ __forceinline__ void gload16(const void* g, void* l) {
  __builtin_amdgcn_global_load_lds(
      (const __attribute__((address_space(1))) unsigned int*)g,
      (__attribute__((address_space(3))) unsigned int*)l, 16, 0, 0);
}

// ================= fragment-major (FM) layout =================
// M[R][K] row-major -> chunk c = rg*(K/32) + kk; lane l holds
// M[rg*16 + (l&15)][kk*32 + (l>>4)*8 .. +8] (one bf16x8, 16B).
// One chunk = ONE contiguous 1KB block.

// ---------------- weights fp32 row-major -> FM bf16 (coalesced reads) --------
template <int LKC>
__global__ __launch_bounds__(256) void permw_kernel(const float* __restrict__ s,
                                                    ushort_t* __restrict__ d, int n8) {
  const int KC = 1 << LKC;
  const int LQ = LKC + 2;             // 8-elem units per row = 4*KC
  int i = blockIdx.x * 256 + threadIdx.x;
  int stride = gridDim.x * 256;
  for (; i < n8; i += stride) {
    int row = i >> LQ;
    int q   = i & ((1 << LQ) - 1);
    int kk = q >> 2, sub = q & 3;
    int rg = row >> 4, lane = (row & 15) + (sub << 4);
    float4 f0 = ((const float4*)s)[(size_t)i * 2];
    float4 f1 = ((const float4*)s)[(size_t)i * 2 + 1];
    ((bf16x8*)d)[((size_t)rg * KC + kk) * 64 + lane] = pack8(f0, f1);
  }
}

// ---------------- x fp32 -> FM bf16 with optional token gather ----------------
template <int LKC>
__global__ __launch_bounds__(256) void gatherA_kernel(const float* __restrict__ x,
                                                      const int* __restrict__ row_token,
                                                      ushort_t* __restrict__ d,
                                                      int n8, int K) {
  const int KC = 1 << LKC;
  int i = blockIdx.x * 256 + threadIdx.x;
  int stride = gridDim.x * 256;
  for (; i < n8; i += stride) {
    int l  = i & 63;
    int fi = i >> 6;
    int kk = fi & (KC - 1);
    int rg = fi >> LKC;
    int row = rg * 16 + (l & 15);
    int tok = row_token ? row_token[row] : row;
    bf16x8 v = {};
    if (tok >= 0) {
      const float* p = x + (size_t)tok * K + kk * 32 + (l >> 4) * 8;
      v = pack8(*(const float4*)p, *(const float4*)(p + 4));
    }
    ((bf16x8*)d)[i] = v;
  }
}

// ---------------- 1) gate ----------------
__global__ __launch_bounds__(64) void gate_kernel(
    const float* __restrict__ x, const float* __restrict__ gw,
    int* __restrict__ topk_idx, float* __restrict__ topk_w, int* __restrict__ counts)
{
  int t = blockIdx.x;
  int lane = threadIdx.x;
  __shared__ float xs[H_DIM];
  __shared__ float lg[E_NUM];
  const float4* xr = (const float4*)(x + (size_t)t * H_DIM);
  ((float4*)xs)[lane] = xr[lane];
  ((float4*)xs)[lane + 64] = xr[lane + 64];
  __syncthreads();
  if (lane < E_NUM) {
    const float* w = gw + (size_t)lane * H_DIM;
    float acc = 0.f;
    #pragma unroll 8
    for (int h = 0; h < H_DIM; h++) acc += xs[h] * w[h];
    lg[lane] = acc;
  }
  __syncthreads();
  if (lane == 0) {
    float mx = lg[0];
    #pragma unroll
    for (int e = 1; e < E_NUM; e++) mx = fmaxf(mx, lg[e]);
    float sc[E_NUM];
    float sum = 0.f;
    #pragma unroll
    for (int e = 0; e < E_NUM; e++) { sc[e] = expf(lg[e] - mx); sum += sc[e]; }
    float inv = 1.f / sum;
    float m1 = -1.f, m2 = -1.f; int i1 = 0, i2 = 0;
    #pragma unroll
    for (int e = 0; e < E_NUM; e++) {
      float s = sc[e] * inv;
      if (s > m1)      { m2 = m1; i2 = i1; m1 = s; i1 = e; }
      else if (s > m2) { m2 = s; i2 = e; }
    }
    topk_idx[t * 2] = i1; topk_idx[t * 2 + 1] = i2;
    topk_w[t * 2] = m1;  topk_w[t * 2 + 1] = m2;
    atomicAdd(&counts[i1], 1);
    atomicAdd(&counts[i2], 1);
  }
}

// ---------------- 2) 128-aligned padded scan + tile->expert maps ----------------
__global__ void offsets_kernel(const int* __restrict__ counts,
                               int* __restrict__ offp, int* __restrict__ cursor,
                               int* __restrict__ rt2e, int* __restrict__ rg2e)
{
  if (threadIdx.x == 0) {
    int acc = 0;
    #pragma unroll
    for (int e = 0; e < E_NUM; e++) { offp[e] = acc; acc += (counts[e] + 127) & ~127; }
    offp[E_NUM] = acc;
    for (int r = 0; r < NRT128; r++) rt2e[r] = -1;
    for (int r = 0; r < NRT64; r++) rg2e[r] = -1;
    for (int e = 0; e < E_NUM; e++) {
      int pc = (counts[e] + 127) & ~127;
      int lo = offp[e];
      for (int r = lo >> 7; r < (lo + pc) >> 7; r++) rt2e[r] = e;
      for (int r = lo >> 6; r < (lo + pc) >> 6; r++) rg2e[r] = e;
    }
  }
  if (threadIdx.x < E_NUM) cursor[threadIdx.x] = 0;
}

// ---------------- 2b) init padded row arrays ----------------
__global__ __launch_bounds__(256) void initrows_kernel(int* __restrict__ row_token) {
  int i = blockIdx.x * 256 + threadIdx.x;
  if (i < RPMAX) row_token[i] = -1;
}

// ---------------- 3) scatter (+ inverse map trow) ----------------
__global__ __launch_bounds__(256) void scatter_kernel(
    const int* __restrict__ topk_idx, const float* __restrict__ topk_w,
    const int* __restrict__ offp, int* __restrict__ cursor,
    int* __restrict__ row_token, int* __restrict__ trow)
{
  int t = blockIdx.x * 256 + threadIdx.x;
  if (t >= T_TOK) return;
  #pragma unroll
  for (int k = 0; k < TOPK; k++) {
    int e = topk_idx[t * 2 + k];
    int pos = atomicAdd(&cursor[e], 1);
    int row = offp[e] + pos;
    row_token[row] = t;
    trow[t * 2 + k] = row;
  }
}

// ---------------- 4) GU GEMM: LDS-staged 2-phase pipelined -------------------
// Tile 128 rows x 128 cols (g & u), 4 waves of 64x64, BK=32, KC=16 steps.
// LDS: sm[6][4096] ushort = 48KB (A dbuf 2x8KB, Bg 2x8KB, Bu 2x8KB).
// Epilogue: silu -> per-wave LDS bounce -> FM inter write.
__global__ __launch_bounds__(256, 2) void gu9_kernel(
    const ushort_t* __restrict__ xgf, const ushort_t* __restrict__ xsf,
    const ushort_t* __restrict__ wgf, const ushort_t* __restrict__ wuf,
    const ushort_t* __restrict__ swgf, const ushort_t* __restrict__ swuf,
    ushort_t* __restrict__ interF, ushort_t* __restrict__ interS,
    const int* __restrict__ rt2e)
{
  const int KC = H_DIM / 32;   // 16
  int bid = blockIdx.x;
  int tid = threadIdx.x, w = tid >> 6, l = tid & 63;
  int wm = w >> 1, wn = w & 1;
  int fr = l & 15, g = l >> 4;

  const bf16x8 *AF, *BGF, *BUF;
  bf16x8* OP;
  int rg0, cg0, kkd0, KCd;

  if (bid < 16 * NRT128) {
    int cb = bid & 15, rt = bid >> 4;
    int e = rt2e[rt]; if (e < 0) return;
    rg0 = rt * 8;
    AF  = (const bf16x8*)xgf;
    BGF = (const bf16x8*)wgf;  BUF = (const bf16x8*)wuf;
    cg0 = e * (I_DIM >> 4) + cb * 8;
    KCd = I_DIM >> 5; kkd0 = cb * 4 + wn * 2;
    OP  = (bf16x8*)interF;
  } else {
    int b2 = bid - 16 * NRT128;
    int cb = b2 & 7, rt = b2 >> 3;
    rg0 = rt * 8;
    AF  = (const bf16x8*)xsf;
    BGF = (const bf16x8*)swgf; BUF = (const bf16x8*)swuf;
    cg0 = cb * 8;
    KCd = IS_DIM >> 5; kkd0 = cb * 4 + wn * 2;
    OP  = (bf16x8*)interS;
  }

  __shared__ ushort_t sm[6][4096];   // [0..1]=A dbuf, [2..3]=Bg, [4..5]=Bu

  // per-wave staging source pointers (chunk base + lane)
  const bf16x8* sa0 = AF  + (size_t)(rg0 + 2 * w)     * KC * 64 + l;
  const bf16x8* sa1 = AF  + (size_t)(rg0 + 2 * w + 1) * KC * 64 + l;
  const bf16x8* sg0 = BGF + (size_t)(cg0 + 2 * w)     * KC * 64 + l;
  const bf16x8* sg1 = BGF + (size_t)(cg0 + 2 * w + 1) * KC * 64 + l;
  const bf16x8* su0 = BUF + (size_t)(cg0 + 2 * w)     * KC * 64 + l;
  const bf16x8* su1 = BUF + (size_t)(cg0 + 2 * w + 1) * KC * 64 + l;
  int s0 = (2 * w) * 512, s1 = (2 * w + 1) * 512;

  f32x4 accg[4][4] = {}, accu[4][4] = {};

  auto stage = [&](int b, int kk) {
    gload16(sa0 + (size_t)kk * 64, &sm[0 + b][s0]);
    gload16(sa1 + (size_t)kk * 64, &sm[0 + b][s1]);
    gload16(sg0 + (size_t)kk * 64, &sm[2 + b][s0]);
    gload16(sg1 + (size_t)kk * 64, &sm[2 + b][s1]);
    gload16(su0 + (size_t)kk * 64, &sm[4 + b][s0]);
    gload16(su1 + (size_t)kk * 64, &sm[4 + b][s1]);
  };
  auto compute = [&](int b) {
    bf16x8 af[4], bg[4], bu[4];
    #pragma unroll
    for (int mi = 0; mi < 4; mi++)
      af[mi] = *(const bf16x8*)&sm[0 + b][(wm * 4 + mi) * 512 + l * 8];
    #pragma unroll
    for (int ni = 0; ni < 4; ni++) {
      bg[ni] = *(const bf16x8*)&sm[2 + b][(wn * 4 + ni) * 512 + l * 8];
      bu[ni] = *(const bf16x8*)&sm[4 + b][(wn * 4 + ni) * 512 + l * 8];
    }
    #pragma unroll
    for (int mi = 0; mi < 4; mi++)
      #pragma unroll
      for (int ni = 0; ni < 4; ni++) {
        accg[mi][ni] = __builtin_amdgcn_mfma_f32_16x16x32_bf16(af[mi], bg[ni], accg[mi][ni], 0, 0, 0);
        accu[mi][ni] = __builtin_amdgcn_mfma_f32_16x16x32_bf16(af[mi], bu[ni], accu[mi][ni], 0, 0, 0);
      }
  };

  stage(0, 0);
  __syncthreads();
  for (int kk = 0; kk < KC; kk += 2) {
    if (kk + 1 < KC) stage(1, kk + 1);
    compute(0);
    __syncthreads();
    if (kk + 2 < KC) stage(0, kk + 2);
    if (kk + 1 < KC) compute(1);
    __syncthreads();
  }

  // epilogue: silu(g)*u -> per-wave bounce (transpose to FM) -> global FM write
  ushort_t* bw = &sm[0][0] + w * (64 * 72);
  #pragma unroll
  for (int mi = 0; mi < 4; mi++)
    #pragma unroll
    for (int ni = 0; ni < 4; ni++)
      #pragma unroll
      for (int j = 0; j < 4; j++) {
        float gg = accg[mi][ni][j], uu = accu[mi][ni][j];
        float s = (gg / (1.f + expf(-gg))) * uu;
        bw[(mi * 16 + g * 4 + j) * 72 + ni * 16 + fr] = f2bf(s);
      }
  #pragma unroll
  for (int rgi = 0; rgi < 4; rgi++)
    #pragma unroll
    for (int kki = 0; kki < 2; kki++) {
      bf16x8 v = *(const bf16x8*)&bw[(rgi * 16 + (l & 15)) * 72 + kki * 32 + (l >> 4) * 8];
      OP[((size_t)(rg0 + wm * 4 + rgi) * KCd + kkd0 + kki) * 64 + l] = v;
    }
}

// ---------------- 5) down GEMM: LDS-staged 2-phase, no atomics ----------------
// Tile 64 rows x 128 cols, 2 waves of 64x64, BK=32, nk steps (64 routed / 32 shared).
// Output: f32 row-major D buffer (per grouped row), combined later.
__global__ __launch_bounds__(128, 3) void down9_kernel(
    const ushort_t* __restrict__ interF, const ushort_t* __restrict__ interS,
    const ushort_t* __restrict__ wdf, const ushort_t* __restrict__ swdf,
    float* __restrict__ Dr, float* __restrict__ Ds,
    const int* __restrict__ rg2e)
{
  int bid = blockIdx.x;
  int tid = threadIdx.x, w = tid >> 6, l = tid & 63;
  int fr = l & 15, g = l >> 4;

  const bf16x8 *AF, *BF;
  float* DO;
  int rgA0, cg0, nk, row0, col0;

  if (bid < 4 * NRT64) {
    int cb = bid & 3, rt = bid >> 2;
    int e = rg2e[rt]; if (e < 0) return;
    AF = (const bf16x8*)interF; BF = (const bf16x8*)wdf;
    rgA0 = rt * 4; cg0 = e * (H_DIM >> 4) + cb * 8;
    nk = I_DIM >> 5;   // 64
    row0 = rt * 64; col0 = cb * 128;
    DO = Dr;
  } else {
    int b2 = bid - 4 * NRT64;
    int cb = b2 & 3, rt = b2 >> 2;
    AF = (const bf16x8*)interS; BF = (const bf16x8*)swdf;
    rgA0 = rt * 4; cg0 = cb * 8;
    nk = IS_DIM >> 5;  // 32
    row0 = rt * 64; col0 = cb * 128;
    DO = Ds;
  }

  __shared__ ushort_t sm[2][6144];   // 12 chunks (4 A + 8 B) x 2 buf = 24KB

  const bf16x8* sa0 = AF + ((size_t)(rgA0 + 2 * w)     * nk) * 64 + l;
  const bf16x8* sa1 = AF + ((size_t)(rgA0 + 2 * w + 1) * nk) * 64 + l;
  const bf16x8* sb0 = BF + ((size_t)(cg0 + 4 * w)      * nk) * 64 + l;
  const bf16x8* sb1 = BF + ((size_t)(cg0 + 4 * w + 1)  * nk) * 64 + l;
  const bf16x8* sb2 = BF + ((size_t)(cg0 + 4 * w + 2)  * nk) * 64 + l;
  const bf16x8* sb3 = BF + ((size_t)(cg0 + 4 * w + 3)  * nk) * 64 + l;

  f32x4 acc[4][4] = {};

  auto stage = [&](int b, int kk) {
    gload16(sa0 + (size_t)kk * 64, &sm[b][(2 * w) * 512]);
    gload16(sa1 + (size_t)kk * 64, &sm[b][(2 * w + 1) * 512]);
    gload16(sb0 + (size_t)kk * 64, &sm[b][(4 + 4 * w) * 512]);
    gload16(sb1 + (size_t)kk * 64, &sm[b][(5 + 4 * w) * 512]);
    gload16(sb2 + (size_t)kk * 64, &sm[b][(6 + 4 * w) * 512]);
    gload16(sb3 + (size_t)kk * 64, &sm[b][(7 + 4 * w) * 512]);
  };
  auto compute = [&](int b) {
    bf16x8 af[4], bf[4];
    #pragma unroll
    for (int mi = 0; mi < 4; mi++)
      af[mi] = *(const bf16x8*)&sm[b][mi * 512 + l * 8];
    #pragma unroll
    for (int ni = 0; ni < 4; ni++)
      bf[ni] = *(const bf16x8*)&sm[b][(4 + w * 4 + ni) * 512 + l * 8];
    #pragma unroll
    for (int mi = 0; mi < 4; mi++)
      #pragma unroll
      for (int ni = 0; ni < 4; ni++)
        acc[mi][ni] = __builtin_amdgcn_mfma_f32_16x16x32_bf16(af[mi], bf[ni], acc[mi][ni], 0, 0, 0);
  };

  stage(0, 0);
  __syncthreads();
  for (int kk = 0; kk < nk; kk += 2) {
    stage(1, kk + 1);
    compute(0);
    __syncthreads();
    if (kk + 2 < nk) stage(0, kk + 2);
    compute(1);
    __syncthreads();
  }

  #pragma unroll
  for (int mi = 0; mi < 4; mi++)
    #pragma unroll
    for (int ni = 0; ni < 4; ni++)
      #pragma unroll
      for (int j = 0; j < 4; j++)
        DO[(size_t)(row0 + mi * 16 + g * 4 + j) * H_DIM + col0 + w * 64 + ni * 16 + fr]
            = acc[mi][ni][j];
}

// ---------------- 6) combine: out[t] = w0*Dr[r0] + w1*Dr[r1] + Ds[t] ----------
__global__ __launch_bounds__(128) void combine_kernel(
    const float* __restrict__ Dr, const float* __restrict__ Ds,
    const int* __restrict__ trow, const float* __restrict__ topk_w,
    float* __restrict__ out)
{
  int t = blockIdx.x, c = threadIdx.x;
  int r0 = trow[t * 2], r1 = trow[t * 2 + 1];
  float w0 = topk_w[t * 2], w1 = topk_w[t * 2 + 1];
  float4 a = ((const float4*)(Dr + (size_t)r0 * H_DIM))[c];
  float4 b = ((const float4*)(Dr + (size_t)r1 * H_DIM))[c];
  float4 s = ((const float4*)(Ds + (size_t)t * H_DIM))[c];
  float4 r;
  r.x = w0 * a.x + w1 * b.x + s.x;
  r.y = w0 * a.y + w1 * b.y + s.y;
  r.z = w0 * a.z + w1 * b.z + s.z;
  r.w = w0 * a.w + w1 * b.w + s.w;
  ((float4*)(out + (size_t)t * H_DIM))[c] = r;
}

// ---------------- launch ----------------
extern "C" void kernel_launch(void* const* d_in, const int* in_sizes, int n_in,
                              void* d_out, int out_size, void* d_ws, size_t ws_size,
                              hipStream_t stream) {
  const float* x       = (const float*)d_in[0];
  const float* gate_w  = (const float*)d_in[1];
  const float* w_gate  = (const float*)d_in[2];
  const float* w_up    = (const float*)d_in[3];
  const float* w_down  = (const float*)d_in[4];
  const float* sw_gate = (const float*)d_in[5];
  const float* sw_up   = (const float*)d_in[6];
  const float* sw_down = (const float*)d_in[7];
  float* out = (float*)d_out;

  char* ws = (char*)d_ws;
  int*   counts    = (int*)ws;                      // 16
  int*   cursor    = (int*)(ws + 64);               // 16
  int*   offp      = (int*)(ws + 128);              // 17
  int*   rt2e      = (int*)(ws + 256);              // 48
  int*   rg2e      = (int*)(ws + 448);              // 96
  int*   topk_idx  = (int*)(ws + 832);              // 4096
  float* topk_w    = (float*)(ws + 17216);          // 4096
  int*   trow      = (int*)(ws + 33600);            // 4096
  int*   row_token = (int*)(ws + 49984);            // RPMAX
  size_t off = 49984 + (size_t)RPMAX * 4;
  off = (off + 255) & ~(size_t)255;
  ushort_t* xgf  = (ushort_t*)(ws + off); off += (size_t)RPMAX * H_DIM * 2;         // 6 MiB
  ushort_t* xsf  = (ushort_t*)(ws + off); off += (size_t)T_TOK * H_DIM * 2;         // 2 MiB
  ushort_t* wgf  = (ushort_t*)(ws + off); off += (size_t)E_NUM * I_DIM * H_DIM * 2; // 32 MiB
  ushort_t* wuf  = (ushort_t*)(ws + off); off += (size_t)E_NUM * I_DIM * H_DIM * 2; // 32 MiB
  ushort_t* wdf  = (ushort_t*)(ws + off); off += (size_t)E_NUM * H_DIM * I_DIM * 2; // 32 MiB
  ushort_t* swgf = (ushort_t*)(ws + off); off += (size_t)IS_DIM * H_DIM * 2;        // 1 MiB
  ushort_t* swuf = (ushort_t*)(ws + off); off += (size_t)IS_DIM * H_DIM * 2;        // 1 MiB
  ushort_t* swdf = (ushort_t*)(ws + off); off += (size_t)H_DIM * IS_DIM * 2;        // 1 MiB
  ushort_t* interF = (ushort_t*)(ws + off); off += (size_t)RPMAX * I_DIM * 2;       // 24 MiB
  ushort_t* interS = (ushort_t*)(ws + off); off += (size_t)T_TOK * IS_DIM * 2;      // 4 MiB
  float*    Dr     = (float*)(ws + off);    off += (size_t)RPMAX * H_DIM * 4;       // 12 MiB
  float*    Ds     = (float*)(ws + off);    off += (size_t)T_TOK * H_DIM * 4;       // 4 MiB

  hipMemsetAsync(counts, 0, 64, stream);
  gate_kernel<<<T_TOK, 64, 0, stream>>>(x, gate_w, topk_idx, topk_w, counts);
  offsets_kernel<<<1, 64, 0, stream>>>(counts, offp, cursor, rt2e, rg2e);
  initrows_kernel<<<RPMAX / 256, 256, 0, stream>>>(row_token);
  scatter_kernel<<<(T_TOK + 255) / 256, 256, 0, stream>>>(topk_idx, topk_w, offp, cursor,
                                                          row_token, trow);
  // A-operands into FM bf16
  gatherA_kernel<4><<<RPMAX * H_DIM / 8 / 256, 256, 0, stream>>>(
      x, row_token, xgf, RPMAX * H_DIM / 8, H_DIM);
  gatherA_kernel<4><<<T_TOK * H_DIM / 8 / 256, 256, 0, stream>>>(
      x, nullptr, xsf, T_TOK * H_DIM / 8, H_DIM);
  // weights into FM bf16
  permw_kernel<4><<<4096, 256, 0, stream>>>(w_gate, wgf, E_NUM * I_DIM * H_DIM / 8);
  permw_kernel<4><<<4096, 256, 0, stream>>>(w_up,   wuf, E_NUM * I_DIM * H_DIM / 8);
  permw_kernel<6><<<4096, 256, 0, stream>>>(w_down, wdf, E_NUM * H_DIM * I_DIM / 8);
  permw_kernel<4><<<256, 256, 0, stream>>>(sw_gate, swgf, IS_DIM * H_DIM / 8);
  permw_kernel<4><<<256, 256, 0, stream>>>(sw_up,   swuf, IS_DIM * H_DIM / 8);
  permw_kernel<5><<<256, 256, 0, stream>>>(sw_down, swdf, H_DIM * IS_DIM / 8);

  // GU: routed (16 cb x 48 rt = 768) + shared (8 cb x 16 rt = 128)
  gu9_kernel<<<16 * NRT128 + 8 * 16, 256, 0, stream>>>(
      xgf, xsf, wgf, wuf, swgf, swuf, interF, interS, rt2e);
  // down: routed (4 cb x 96 rt = 384) + shared (4 cb x 32 rt = 128)
  down9_kernel<<<4 * NRT64 + 4 * 32, 128, 0, stream>>>(
      interF, interS, wdf, swdf, Dr, Ds, rg2e);
  // combine
  combine_kernel<<<T_TOK, 128, 0, stream>>>(Dr, Ds, trow, topk_w, out);
}

// Round 10
// 271.707 us; speedup vs baseline: 1.2112x; 1.0535x over previous
//
#include <hip/hip_runtime.h>
#include <hip/hip_bf16.h>
#include <math.h>

// ---------------- problem constants ----------------
#define T_TOK 2048
#define H_DIM 512
#define E_NUM 16
#define TOPK  2
#define I_DIM 2048
#define IS_DIM 1024
#define RPMAX 6144             // padded grouped rows (128-aligned per expert)
#define NRT128 (RPMAX / 128)   // 48
#define NRT64  (RPMAX / 64)    // 96

typedef __attribute__((ext_vector_type(8))) short bf16x8;
typedef __attribute__((ext_vector_type(4))) float f32x4;
typedef unsigned short ushort_t;

static __device__ __forceinline__ unsigned short f2bf(float f) {
  unsigned int u = __float_as_uint(f);
  unsigned int r = (u + 0x7fffu + ((u >> 16) & 1u)) >> 16;   // RNE
  return (unsigned short)r;
}

static __device__ __forceinline__ bf16x8 pack8(float4 a, float4 b) {
  bf16x8 v;
  v[0] = (short)f2bf(a.x); v[1] = (short)f2bf(a.y);
  v[2] = (short)f2bf(a.z); v[3] = (short)f2bf(a.w);
  v[4] = (short)f2bf(b.x); v[5] = (short)f2bf(b.y);
  v[6] = (short)f2bf(b.z); v[7] = (short)f2bf(b.w);
  return v;
}

// async global->LDS, 16B/lane: global src per-lane, LDS dst wave-uniform+lane*16
static __device__ __forceinline__ void gload16(const void* g, void* l) {
  __builtin_amdgcn_global_load_lds(
      (const __attribute__((address_space(1))) unsigned int*)g,
      (__attribute__((address_space(3))) unsigned int*)l, 16, 0, 0);
}

// ================= fragment-major (FM) layout =================
// M[R][K] row-major -> chunk c = rg*(K/32) + kk; lane l holds
// M[rg*16 + (l&15)][kk*32 + (l>>4)*8 .. +8] (one bf16x8, 16B).
// One chunk = ONE contiguous 1KB block.

// ---------------- weights fp32 row-major -> FM bf16 (coalesced reads) --------
template <int LKC>
__global__ __launch_bounds__(256) void permw_kernel(const float* __restrict__ s,
                                                    ushort_t* __restrict__ d, int n8) {
  const int KC = 1 << LKC;
  const int LQ = LKC + 2;             // 8-elem units per row = 4*KC
  int i = blockIdx.x * 256 + threadIdx.x;
  int stride = gridDim.x * 256;
  for (; i < n8; i += stride) {
    int row = i >> LQ;
    int q   = i & ((1 << LQ) - 1);
    int kk = q >> 2, sub = q & 3;
    int rg = row >> 4, lane = (row & 15) + (sub << 4);
    float4 f0 = ((const float4*)s)[(size_t)i * 2];
    float4 f1 = ((const float4*)s)[(size_t)i * 2 + 1];
    ((bf16x8*)d)[((size_t)rg * KC + kk) * 64 + lane] = pack8(f0, f1);
  }
}

// ---------------- x fp32 -> FM bf16 with optional token gather ----------------
template <int LKC>
__global__ __launch_bounds__(256) void gatherA_kernel(const float* __restrict__ x,
                                                      const int* __restrict__ row_token,
                                                      ushort_t* __restrict__ d,
                                                      int n8, int K) {
  const int KC = 1 << LKC;
  int i = blockIdx.x * 256 + threadIdx.x;
  int stride = gridDim.x * 256;
  for (; i < n8; i += stride) {
    int l  = i & 63;
    int fi = i >> 6;
    int kk = fi & (KC - 1);
    int rg = fi >> LKC;
    int row = rg * 16 + (l & 15);
    int tok = row_token ? row_token[row] : row;
    bf16x8 v = {};
    if (tok >= 0) {
      const float* p = x + (size_t)tok * K + kk * 32 + (l >> 4) * 8;
      v = pack8(*(const float4*)p, *(const float4*)(p + 4));
    }
    ((bf16x8*)d)[i] = v;
  }
}

// ---------------- 1) gate: wave-parallel logits -> softmax -> top2 ----------
// Block = 256 thr = 4 waves = 4 tokens. gw staged to padded LDS once/block.
// Lane l: expert e = l&15, k-slice g = l>>4 (128 FMA), shfl_xor(16,32) reduce.
__global__ __launch_bounds__(256) void gate2_kernel(
    const float* __restrict__ x, const float* __restrict__ gw,
    int* __restrict__ topk_idx, float* __restrict__ topk_w, int* __restrict__ counts)
{
  __shared__ float gws[E_NUM][516];   // padded stride (bank-spread)
  __shared__ float xs[4][520];
  __shared__ float lgs[4][16];
  int tid = threadIdx.x;
  // stage gw (16x512 = 2048 float4, coalesced)
  for (int i = tid; i < 2048; i += 256) {
    int e = i >> 7, q = i & 127;
    float4 v = ((const float4*)gw)[i];
    *(float4*)&gws[e][q * 4] = v;
  }
  int w = tid >> 6, l = tid & 63;
  int t = blockIdx.x * 4 + w;
  // stage this wave's x row (512 floats)
  const float4* xr4 = (const float4*)(x + (size_t)t * H_DIM);
  *(float4*)&xs[w][l * 8]     = xr4[l * 2];
  *(float4*)&xs[w][l * 8 + 4] = xr4[l * 2 + 1];
  __syncthreads();

  int e = l & 15, g = l >> 4;
  const float* gr = &gws[e][0];
  const float* xr = &xs[w][0];
  float p = 0.f;
  #pragma unroll
  for (int it = 0; it < 16; it++) {
    int h = it * 32 + g * 8;
    float4 a0 = *(const float4*)&xr[h];
    float4 a1 = *(const float4*)&xr[h + 4];
    float4 b0 = *(const float4*)&gr[h];
    float4 b1 = *(const float4*)&gr[h + 4];
    p += a0.x * b0.x + a0.y * b0.y + a0.z * b0.z + a0.w * b0.w
       + a1.x * b1.x + a1.y * b1.y + a1.z * b1.z + a1.w * b1.w;
  }
  p += __shfl_xor(p, 16);
  p += __shfl_xor(p, 32);
  if (l < 16) lgs[w][l] = p;
  __syncthreads();

  if (l == 0) {
    float lg[E_NUM];
    #pragma unroll
    for (int i = 0; i < E_NUM; i++) lg[i] = lgs[w][i];
    float mx = lg[0];
    #pragma unroll
    for (int i = 1; i < E_NUM; i++) mx = fmaxf(mx, lg[i]);
    float sc[E_NUM];
    float sum = 0.f;
    #pragma unroll
    for (int i = 0; i < E_NUM; i++) { sc[i] = expf(lg[i] - mx); sum += sc[i]; }
    float inv = 1.f / sum;
    float m1 = -1.f, m2 = -1.f; int i1 = 0, i2 = 0;
    #pragma unroll
    for (int i = 0; i < E_NUM; i++) {
      float s = sc[i] * inv;
      if (s > m1)      { m2 = m1; i2 = i1; m1 = s; i1 = i; }
      else if (s > m2) { m2 = s; i2 = i; }
    }
    topk_idx[t * 2] = i1; topk_idx[t * 2 + 1] = i2;
    topk_w[t * 2] = m1;  topk_w[t * 2 + 1] = m2;
    atomicAdd(&counts[i1], 1);
    atomicAdd(&counts[i2], 1);
  }
}

// ---------------- 2) 128-aligned padded scan + tile->expert maps ----------------
__global__ void offsets_kernel(const int* __restrict__ counts,
                               int* __restrict__ offp, int* __restrict__ cursor,
                               int* __restrict__ rt2e, int* __restrict__ rg2e)
{
  if (threadIdx.x == 0) {
    int acc = 0;
    #pragma unroll
    for (int e = 0; e < E_NUM; e++) { offp[e] = acc; acc += (counts[e] + 127) & ~127; }
    offp[E_NUM] = acc;
    for (int r = 0; r < NRT128; r++) rt2e[r] = -1;
    for (int r = 0; r < NRT64; r++) rg2e[r] = -1;
    for (int e = 0; e < E_NUM; e++) {
      int pc = (counts[e] + 127) & ~127;
      int lo = offp[e];
      for (int r = lo >> 7; r < (lo + pc) >> 7; r++) rt2e[r] = e;
      for (int r = lo >> 6; r < (lo + pc) >> 6; r++) rg2e[r] = e;
    }
  }
  if (threadIdx.x < E_NUM) cursor[threadIdx.x] = 0;
}

// ---------------- 2b) init padded row arrays ----------------
__global__ __launch_bounds__(256) void initrows_kernel(int* __restrict__ row_token) {
  int i = blockIdx.x * 256 + threadIdx.x;
  if (i < RPMAX) row_token[i] = -1;
}

// ---------------- 3) scatter (+ inverse map trow) ----------------
__global__ __launch_bounds__(256) void scatter_kernel(
    const int* __restrict__ topk_idx, const float* __restrict__ topk_w,
    const int* __restrict__ offp, int* __restrict__ cursor,
    int* __restrict__ row_token, int* __restrict__ trow)
{
  int t = blockIdx.x * 256 + threadIdx.x;
  if (t >= T_TOK) return;
  #pragma unroll
  for (int k = 0; k < TOPK; k++) {
    int e = topk_idx[t * 2 + k];
    int pos = atomicAdd(&cursor[e], 1);
    int row = offp[e] + pos;
    row_token[row] = t;
    trow[t * 2 + k] = row;
  }
}

// ---------------- 4) GU GEMM: LDS-staged 2-phase pipelined -------------------
// Tile 128 rows x 128 cols (g & u), 4 waves of 64x64, BK=32, KC=16 steps.
__global__ __launch_bounds__(256, 2) void gu9_kernel(
    const ushort_t* __restrict__ xgf, const ushort_t* __restrict__ xsf,
    const ushort_t* __restrict__ wgf, const ushort_t* __restrict__ wuf,
    const ushort_t* __restrict__ swgf, const ushort_t* __restrict__ swuf,
    ushort_t* __restrict__ interF, ushort_t* __restrict__ interS,
    const int* __restrict__ rt2e)
{
  const int KC = H_DIM / 32;   // 16
  int bid = blockIdx.x;
  int tid = threadIdx.x, w = tid >> 6, l = tid & 63;
  int wm = w >> 1, wn = w & 1;
  int fr = l & 15, g = l >> 4;

  const bf16x8 *AF, *BGF, *BUF;
  bf16x8* OP;
  int rg0, cg0, kkd0, KCd;

  if (bid < 16 * NRT128) {
    int cb = bid & 15, rt = bid >> 4;
    int e = rt2e[rt]; if (e < 0) return;
    rg0 = rt * 8;
    AF  = (const bf16x8*)xgf;
    BGF = (const bf16x8*)wgf;  BUF = (const bf16x8*)wuf;
    cg0 = e * (I_DIM >> 4) + cb * 8;
    KCd = I_DIM >> 5; kkd0 = cb * 4 + wn * 2;
    OP  = (bf16x8*)interF;
  } else {
    int b2 = bid - 16 * NRT128;
    int cb = b2 & 7, rt = b2 >> 3;
    rg0 = rt * 8;
    AF  = (const bf16x8*)xsf;
    BGF = (const bf16x8*)swgf; BUF = (const bf16x8*)swuf;
    cg0 = cb * 8;
    KCd = IS_DIM >> 5; kkd0 = cb * 4 + wn * 2;
    OP  = (bf16x8*)interS;
  }

  __shared__ ushort_t sm[6][4096];   // [0..1]=A dbuf, [2..3]=Bg, [4..5]=Bu

  const bf16x8* sa0 = AF  + (size_t)(rg0 + 2 * w)     * KC * 64 + l;
  const bf16x8* sa1 = AF  + (size_t)(rg0 + 2 * w + 1) * KC * 64 + l;
  const bf16x8* sg0 = BGF + (size_t)(cg0 + 2 * w)     * KC * 64 + l;
  const bf16x8* sg1 = BGF + (size_t)(cg0 + 2 * w + 1) * KC * 64 + l;
  const bf16x8* su0 = BUF + (size_t)(cg0 + 2 * w)     * KC * 64 + l;
  const bf16x8* su1 = BUF + (size_t)(cg0 + 2 * w + 1) * KC * 64 + l;
  int s0 = (2 * w) * 512, s1 = (2 * w + 1) * 512;

  f32x4 accg[4][4] = {}, accu[4][4] = {};

  auto stage = [&](int b, int kk) {
    gload16(sa0 + (size_t)kk * 64, &sm[0 + b][s0]);
    gload16(sa1 + (size_t)kk * 64, &sm[0 + b][s1]);
    gload16(sg0 + (size_t)kk * 64, &sm[2 + b][s0]);
    gload16(sg1 + (size_t)kk * 64, &sm[2 + b][s1]);
    gload16(su0 + (size_t)kk * 64, &sm[4 + b][s0]);
    gload16(su1 + (size_t)kk * 64, &sm[4 + b][s1]);
  };
  auto compute = [&](int b) {
    bf16x8 af[4], bg[4], bu[4];
    #pragma unroll
    for (int mi = 0; mi < 4; mi++)
      af[mi] = *(const bf16x8*)&sm[0 + b][(wm * 4 + mi) * 512 + l * 8];
    #pragma unroll
    for (int ni = 0; ni < 4; ni++) {
      bg[ni] = *(const bf16x8*)&sm[2 + b][(wn * 4 + ni) * 512 + l * 8];
      bu[ni] = *(const bf16x8*)&sm[4 + b][(wn * 4 + ni) * 512 + l * 8];
    }
    #pragma unroll
    for (int mi = 0; mi < 4; mi++)
      #pragma unroll
      for (int ni = 0; ni < 4; ni++) {
        accg[mi][ni] = __builtin_amdgcn_mfma_f32_16x16x32_bf16(af[mi], bg[ni], accg[mi][ni], 0, 0, 0);
        accu[mi][ni] = __builtin_amdgcn_mfma_f32_16x16x32_bf16(af[mi], bu[ni], accu[mi][ni], 0, 0, 0);
      }
  };

  stage(0, 0);
  __syncthreads();
  for (int kk = 0; kk < KC; kk += 2) {
    if (kk + 1 < KC) stage(1, kk + 1);
    compute(0);
    __syncthreads();
    if (kk + 2 < KC) stage(0, kk + 2);
    if (kk + 1 < KC) compute(1);
    __syncthreads();
  }

  // epilogue: silu(g)*u -> per-wave bounce (transpose to FM) -> global FM write
  ushort_t* bw = &sm[0][0] + w * (64 * 72);
  #pragma unroll
  for (int mi = 0; mi < 4; mi++)
    #pragma unroll
    for (int ni = 0; ni < 4; ni++)
      #pragma unroll
      for (int j = 0; j < 4; j++) {
        float gg = accg[mi][ni][j], uu = accu[mi][ni][j];
        float s = (gg / (1.f + expf(-gg))) * uu;
        bw[(mi * 16 + g * 4 + j) * 72 + ni * 16 + fr] = f2bf(s);
      }
  #pragma unroll
  for (int rgi = 0; rgi < 4; rgi++)
    #pragma unroll
    for (int kki = 0; kki < 2; kki++) {
      bf16x8 v = *(const bf16x8*)&bw[(rgi * 16 + (l & 15)) * 72 + kki * 32 + (l >> 4) * 8];
      OP[((size_t)(rg0 + wm * 4 + rgi) * KCd + kkd0 + kki) * 64 + l] = v;
    }
}

// ---------------- 5) down GEMM: LDS-staged 2-phase, no atomics ----------------
__global__ __launch_bounds__(128, 3) void down9_kernel(
    const ushort_t* __restrict__ interF, const ushort_t* __restrict__ interS,
    const ushort_t* __restrict__ wdf, const ushort_t* __restrict__ swdf,
    float* __restrict__ Dr, float* __restrict__ Ds,
    const int* __restrict__ rg2e)
{
  int bid = blockIdx.x;
  int tid = threadIdx.x, w = tid >> 6, l = tid & 63;
  int fr = l & 15, g = l >> 4;

  const bf16x8 *AF, *BF;
  float* DO;
  int rgA0, cg0, nk, row0, col0;

  if (bid < 4 * NRT64) {
    int cb = bid & 3, rt = bid >> 2;
    int e = rg2e[rt]; if (e < 0) return;
    AF = (const bf16x8*)interF; BF = (const bf16x8*)wdf;
    rgA0 = rt * 4; cg0 = e * (H_DIM >> 4) + cb * 8;
    nk = I_DIM >> 5;   // 64
    row0 = rt * 64; col0 = cb * 128;
    DO = Dr;
  } else {
    int b2 = bid - 4 * NRT64;
    int cb = b2 & 3, rt = b2 >> 2;
    AF = (const bf16x8*)interS; BF = (const bf16x8*)swdf;
    rgA0 = rt * 4; cg0 = cb * 8;
    nk = IS_DIM >> 5;  // 32
    row0 = rt * 64; col0 = cb * 128;
    DO = Ds;
  }

  __shared__ ushort_t sm[2][6144];   // 12 chunks (4 A + 8 B) x 2 buf = 24KB

  const bf16x8* sa0 = AF + ((size_t)(rgA0 + 2 * w)     * nk) * 64 + l;
  const bf16x8* sa1 = AF + ((size_t)(rgA0 + 2 * w + 1) * nk) * 64 + l;
  const bf16x8* sb0 = BF + ((size_t)(cg0 + 4 * w)      * nk) * 64 + l;
  const bf16x8* sb1 = BF + ((size_t)(cg0 + 4 * w + 1)  * nk) * 64 + l;
  const bf16x8* sb2 = BF + ((size_t)(cg0 + 4 * w + 2)  * nk) * 64 + l;
  const bf16x8* sb3 = BF + ((size_t)(cg0 + 4 * w + 3)  * nk) * 64 + l;

  f32x4 acc[4][4] = {};

  auto stage = [&](int b, int kk) {
    gload16(sa0 + (size_t)kk * 64, &sm[b][(2 * w) * 512]);
    gload16(sa1 + (size_t)kk * 64, &sm[b][(2 * w + 1) * 512]);
    gload16(sb0 + (size_t)kk * 64, &sm[b][(4 + 4 * w) * 512]);
    gload16(sb1 + (size_t)kk * 64, &sm[b][(5 + 4 * w) * 512]);
    gload16(sb2 + (size_t)kk * 64, &sm[b][(6 + 4 * w) * 512]);
    gload16(sb3 + (size_t)kk * 64, &sm[b][(7 + 4 * w) * 512]);
  };
  auto compute = [&](int b) {
    bf16x8 af[4], bf[4];
    #pragma unroll
    for (int mi = 0; mi < 4; mi++)
      af[mi] = *(const bf16x8*)&sm[b][mi * 512 + l * 8];
    #pragma unroll
    for (int ni = 0; ni < 4; ni++)
      bf[ni] = *(const bf16x8*)&sm[b][(4 + w * 4 + ni) * 512 + l * 8];
    #pragma unroll
    for (int mi = 0; mi < 4; mi++)
      #pragma unroll
      for (int ni = 0; ni < 4; ni++)
        acc[mi][ni] = __builtin_amdgcn_mfma_f32_16x16x32_bf16(af[mi], bf[ni], acc[mi][ni], 0, 0, 0);
  };

  stage(0, 0);
  __syncthreads();
  for (int kk = 0; kk < nk; kk += 2) {
    stage(1, kk + 1);
    compute(0);
    __syncthreads();
    if (kk + 2 < nk) stage(0, kk + 2);
    compute(1);
    __syncthreads();
  }

  #pragma unroll
  for (int mi = 0; mi < 4; mi++)
    #pragma unroll
    for (int ni = 0; ni < 4; ni++)
      #pragma unroll
      for (int j = 0; j < 4; j++)
        DO[(size_t)(row0 + mi * 16 + g * 4 + j) * H_DIM + col0 + w * 64 + ni * 16 + fr]
            = acc[mi][ni][j];
}

// ---------------- 6) combine: out[t] = w0*Dr[r0] + w1*Dr[r1] + Ds[t] ----------
__global__ __launch_bounds__(128) void combine_kernel(
    const float* __restrict__ Dr, const float* __restrict__ Ds,
    const int* __restrict__ trow, const float* __restrict__ topk_w,
    float* __restrict__ out)
{
  int t = blockIdx.x, c = threadIdx.x;
  int r0 = trow[t * 2], r1 = trow[t * 2 + 1];
  float w0 = topk_w[t * 2], w1 = topk_w[t * 2 + 1];
  float4 a = ((const float4*)(Dr + (size_t)r0 * H_DIM))[c];
  float4 b = ((const float4*)(Dr + (size_t)r1 * H_DIM))[c];
  float4 s = ((const float4*)(Ds + (size_t)t * H_DIM))[c];
  float4 r;
  r.x = w0 * a.x + w1 * b.x + s.x;
  r.y = w0 * a.y + w1 * b.y + s.y;
  r.z = w0 * a.z + w1 * b.z + s.z;
  r.w = w0 * a.w + w1 * b.w + s.w;
  ((float4*)(out + (size_t)t * H_DIM))[c] = r;
}

// ---------------- launch ----------------
extern "C" void kernel_launch(void* const* d_in, const int* in_sizes, int n_in,
                              void* d_out, int out_size, void* d_ws, size_t ws_size,
                              hipStream_t stream) {
  const float* x       = (const float*)d_in[0];
  const float* gate_w  = (const float*)d_in[1];
  const float* w_gate  = (const float*)d_in[2];
  const float* w_up    = (const float*)d_in[3];
  const float* w_down  = (const float*)d_in[4];
  const float* sw_gate = (const float*)d_in[5];
  const float* sw_up   = (const float*)d_in[6];
  const float* sw_down = (const float*)d_in[7];
  float* out = (float*)d_out;

  char* ws = (char*)d_ws;
  int*   counts    = (int*)ws;                      // 16
  int*   cursor    = (int*)(ws + 64);               // 16
  int*   offp      = (int*)(ws + 128);              // 17
  int*   rt2e      = (int*)(ws + 256);              // 48
  int*   rg2e      = (int*)(ws + 448);              // 96
  int*   topk_idx  = (int*)(ws + 832);              // 4096
  float* topk_w    = (float*)(ws + 17216);          // 4096
  int*   trow      = (int*)(ws + 33600);            // 4096
  int*   row_token = (int*)(ws + 49984);            // RPMAX
  size_t off = 49984 + (size_t)RPMAX * 4;
  off = (off + 255) & ~(size_t)255;
  ushort_t* xgf  = (ushort_t*)(ws + off); off += (size_t)RPMAX * H_DIM * 2;         // 6 MiB
  ushort_t* xsf  = (ushort_t*)(ws + off); off += (size_t)T_TOK * H_DIM * 2;         // 2 MiB
  ushort_t* wgf  = (ushort_t*)(ws + off); off += (size_t)E_NUM * I_DIM * H_DIM * 2; // 32 MiB
  ushort_t* wuf  = (ushort_t*)(ws + off); off += (size_t)E_NUM * I_DIM * H_DIM * 2; // 32 MiB
  ushort_t* wdf  = (ushort_t*)(ws + off); off += (size_t)E_NUM * H_DIM * I_DIM * 2; // 32 MiB
  ushort_t* swgf = (ushort_t*)(ws + off); off += (size_t)IS_DIM * H_DIM * 2;        // 1 MiB
  ushort_t* swuf = (ushort_t*)(ws + off); off += (size_t)IS_DIM * H_DIM * 2;        // 1 MiB
  ushort_t* swdf = (ushort_t*)(ws + off); off += (size_t)H_DIM * IS_DIM * 2;        // 1 MiB
  ushort_t* interF = (ushort_t*)(ws + off); off += (size_t)RPMAX * I_DIM * 2;       // 24 MiB
  ushort_t* interS = (ushort_t*)(ws + off); off += (size_t)T_TOK * IS_DIM * 2;      // 4 MiB
  float*    Dr     = (float*)(ws + off);    off += (size_t)RPMAX * H_DIM * 4;       // 12 MiB
  float*    Ds     = (float*)(ws + off);    off += (size_t)T_TOK * H_DIM * 4;       // 4 MiB

  hipMemsetAsync(counts, 0, 64, stream);
  gate2_kernel<<<T_TOK / 4, 256, 0, stream>>>(x, gate_w, topk_idx, topk_w, counts);
  offsets_kernel<<<1, 64, 0, stream>>>(counts, offp, cursor, rt2e, rg2e);
  initrows_kernel<<<RPMAX / 256, 256, 0, stream>>>(row_token);
  scatter_kernel<<<(T_TOK + 255) / 256, 256, 0, stream>>>(topk_idx, topk_w, offp, cursor,
                                                          row_token, trow);
  // A-operands into FM bf16
  gatherA_kernel<4><<<RPMAX * H_DIM / 8 / 256, 256, 0, stream>>>(
      x, row_token, xgf, RPMAX * H_DIM / 8, H_DIM);
  gatherA_kernel<4><<<T_TOK * H_DIM / 8 / 256, 256, 0, stream>>>(
      x, nullptr, xsf, T_TOK * H_DIM / 8, H_DIM);
  // weights into FM bf16
  permw_kernel<4><<<4096, 256, 0, stream>>>(w_gate, wgf, E_NUM * I_DIM * H_DIM / 8);
  permw_kernel<4><<<4096, 256, 0, stream>>>(w_up,   wuf, E_NUM * I_DIM * H_DIM / 8);
  permw_kernel<6><<<4096, 256, 0, stream>>>(w_down, wdf, E_NUM * H_DIM * I_DIM / 8);
  permw_kernel<4><<<256, 256, 0, stream>>>(sw_gate, swgf, IS_DIM * H_DIM / 8);
  permw_kernel<4><<<256, 256, 0, stream>>>(sw_up,   swuf, IS_DIM * H_DIM / 8);
  permw_kernel<5><<<256, 256, 0, stream>>>(sw_down, swdf, H_DIM * IS_DIM / 8);

  // GU: routed (16 cb x 48 rt = 768) + shared (8 cb x 16 rt = 128)
  gu9_kernel<<<16 * NRT128 + 8 * 16, 256, 0, stream>>>(
      xgf, xsf, wgf, wuf, swgf, swuf, interF, interS, rt2e);
  // down: routed (4 cb x 96 rt = 384) + shared (4 cb x 32 rt = 128)
  down9_kernel<<<4 * NRT64 + 4 * 32, 128, 0, stream>>>(
      interF, interS, wdf, swdf, Dr, Ds, rg2e);
  // combine
  combine_kernel<<<T_TOK, 128, 0, stream>>>(Dr, Ds, trow, topk_w, out);
}

// Round 11
// 228.817 us; speedup vs baseline: 1.4383x; 1.1874x over previous
//
#include <hip/hip_runtime.h>
#include <hip/hip_bf16.h>
#include <math.h>

// ---------------- problem constants ----------------
#define T_TOK 2048
#define H_DIM 512
#define E_NUM 16
#define TOPK  2
#define I_DIM 2048
#define IS_DIM 1024
#define RPMAX 6144             // padded grouped rows (128-aligned per expert)
#define NRT128 (RPMAX / 128)   // 48
#define NRT64  (RPMAX / 64)    // 96

typedef __attribute__((ext_vector_type(8))) short bf16x8;
typedef __attribute__((ext_vector_type(4))) float f32x4;
typedef unsigned short ushort_t;

static __device__ __forceinline__ unsigned short f2bf(float f) {
  unsigned int u = __float_as_uint(f);
  unsigned int r = (u + 0x7fffu + ((u >> 16) & 1u)) >> 16;   // RNE
  return (unsigned short)r;
}

static __device__ __forceinline__ bf16x8 pack8(float4 a, float4 b) {
  bf16x8 v;
  v[0] = (short)f2bf(a.x); v[1] = (short)f2bf(a.y);
  v[2] = (short)f2bf(a.z); v[3] = (short)f2bf(a.w);
  v[4] = (short)f2bf(b.x); v[5] = (short)f2bf(b.y);
  v[6] = (short)f2bf(b.z); v[7] = (short)f2bf(b.w);
  return v;
}

// async global->LDS, 16B/lane: global src per-lane, LDS dst wave-uniform+lane*16
static __device__ __forceinline__ void gload16(const void* g, void* l) {
  __builtin_amdgcn_global_load_lds(
      (const __attribute__((address_space(1))) unsigned int*)g,
      (__attribute__((address_space(3))) unsigned int*)l, 16, 0, 0);
}

// ================= fragment-major (FM) layout =================
// M[R][K] row-major -> chunk c = rg*(K/32) + kk; lane l holds
// M[rg*16 + (l&15)][kk*32 + (l>>4)*8 .. +8] (one bf16x8, 16B).
// One chunk = ONE contiguous 1KB block.

// ---------------- weights fp32 row-major -> FM bf16 (coalesced reads) --------
template <int LKC>
__global__ __launch_bounds__(256) void permw_kernel(const float* __restrict__ s,
                                                    ushort_t* __restrict__ d, int n8) {
  const int KC = 1 << LKC;
  const int LQ = LKC + 2;             // 8-elem units per row = 4*KC
  int i = blockIdx.x * 256 + threadIdx.x;
  int stride = gridDim.x * 256;
  for (; i < n8; i += stride) {
    int row = i >> LQ;
    int q   = i & ((1 << LQ) - 1);
    int kk = q >> 2, sub = q & 3;
    int rg = row >> 4, lane = (row & 15) + (sub << 4);
    float4 f0 = ((const float4*)s)[(size_t)i * 2];
    float4 f1 = ((const float4*)s)[(size_t)i * 2 + 1];
    ((bf16x8*)d)[((size_t)rg * KC + kk) * 64 + lane] = pack8(f0, f1);
  }
}

// ---------------- x fp32 -> FM bf16 with optional token gather ----------------
template <int LKC>
__global__ __launch_bounds__(256) void gatherA_kernel(const float* __restrict__ x,
                                                      const int* __restrict__ row_token,
                                                      ushort_t* __restrict__ d,
                                                      int n8, int K) {
  const int KC = 1 << LKC;
  int i = blockIdx.x * 256 + threadIdx.x;
  int stride = gridDim.x * 256;
  for (; i < n8; i += stride) {
    int l  = i & 63;
    int fi = i >> 6;
    int kk = fi & (KC - 1);
    int rg = fi >> LKC;
    int row = rg * 16 + (l & 15);
    int tok = row_token ? row_token[row] : row;
    bf16x8 v = {};
    if (tok >= 0) {
      const float* p = x + (size_t)tok * K + kk * 32 + (l >> 4) * 8;
      v = pack8(*(const float4*)p, *(const float4*)(p + 4));
    }
    ((bf16x8*)d)[i] = v;
  }
}

// ---------------- 1a) logits GEMV: logits[t][e] = dot(x[t], gw[e]) ----------
// Block = 256 thr = 16 tokens x 16 experts. x rows staged in padded LDS.
// gw rows read wave-broadcast (4 segments/instr) from L2; per-block k-rotation.
__global__ __launch_bounds__(256) void logits_kernel(
    const float* __restrict__ x, const float* __restrict__ gw,
    float* __restrict__ logits)
{
  __shared__ float xs[16][516];
  int tid = threadIdx.x;
  int t0 = blockIdx.x * 16;
  for (int i = tid; i < 2048; i += 256) {   // 16 rows x 128 float4, coalesced
    int tt = i >> 7, q = i & 127;
    float4 v = ((const float4*)(x + (size_t)(t0 + tt) * H_DIM))[q];
    *(float4*)&xs[tt][q * 4] = v;
  }
  __syncthreads();
  int e = tid >> 4, tt = tid & 15;
  const float* gr = gw + (size_t)e * H_DIM;
  const float* xr = &xs[tt][0];
  int kbase = (blockIdx.x & 7) << 6;        // stagger L2 hotspot
  float acc = 0.f;
  #pragma unroll 8
  for (int kk = 0; kk < H_DIM; kk += 4) {
    int k = (kbase + kk) & (H_DIM - 1);
    float4 b = *(const float4*)(gr + k);
    float4 a = *(const float4*)(xr + k);
    acc += a.x * b.x + a.y * b.y + a.z * b.z + a.w * b.w;
  }
  logits[(size_t)(t0 + tt) * E_NUM + e] = acc;
}

// ---------------- 1b) softmax + top2 + histogram counts ----------------
// One token per thread; per-block LDS histogram -> 16 global atomics/block.
__global__ __launch_bounds__(256) void topk_kernel(
    const float* __restrict__ logits,
    int* __restrict__ topk_idx, float* __restrict__ topk_w, int* __restrict__ counts)
{
  __shared__ int hist[E_NUM];
  int tid = threadIdx.x;
  if (tid < E_NUM) hist[tid] = 0;
  __syncthreads();
  int t = blockIdx.x * 256 + tid;
  float lg[E_NUM];
  #pragma unroll
  for (int i = 0; i < 4; i++) {
    float4 v = ((const float4*)(logits + (size_t)t * E_NUM))[i];
    lg[i * 4] = v.x; lg[i * 4 + 1] = v.y; lg[i * 4 + 2] = v.z; lg[i * 4 + 3] = v.w;
  }
  float mx = lg[0];
  #pragma unroll
  for (int i = 1; i < E_NUM; i++) mx = fmaxf(mx, lg[i]);
  float sc[E_NUM];
  float sum = 0.f;
  #pragma unroll
  for (int i = 0; i < E_NUM; i++) { sc[i] = expf(lg[i] - mx); sum += sc[i]; }
  float inv = 1.f / sum;
  float m1 = -1.f, m2 = -1.f; int i1 = 0, i2 = 0;
  #pragma unroll
  for (int i = 0; i < E_NUM; i++) {
    float s = sc[i] * inv;
    if (s > m1)      { m2 = m1; i2 = i1; m1 = s; i1 = i; }
    else if (s > m2) { m2 = s; i2 = i; }
  }
  topk_idx[t * 2] = i1; topk_idx[t * 2 + 1] = i2;
  topk_w[t * 2] = m1;  topk_w[t * 2 + 1] = m2;
  atomicAdd(&hist[i1], 1);
  atomicAdd(&hist[i2], 1);
  __syncthreads();
  if (tid < E_NUM) atomicAdd(&counts[tid], hist[tid]);
}

// ---------------- 2) 128-aligned padded scan + tile->expert maps (parallel) ---
__global__ void offsets_kernel(const int* __restrict__ counts,
                               int* __restrict__ offp, int* __restrict__ cursor,
                               int* __restrict__ rt2e, int* __restrict__ rg2e)
{
  __shared__ int offs[E_NUM + 1];
  int tid = threadIdx.x;
  if (tid == 0) {
    int acc = 0;
    #pragma unroll
    for (int e = 0; e < E_NUM; e++) {
      offs[e] = acc; offp[e] = acc;
      acc += (counts[e] + 127) & ~127;
    }
    offs[E_NUM] = acc; offp[E_NUM] = acc;
  }
  if (tid < E_NUM) cursor[tid] = 0;
  __syncthreads();
  for (int r = tid; r < NRT128; r += 128) {
    int row = r << 7; int e = -1;
    #pragma unroll
    for (int i = 0; i < E_NUM; i++)
      if (row >= offs[i] && row < offs[i + 1]) e = i;
    rt2e[r] = e;
  }
  for (int r = tid; r < NRT64; r += 128) {
    int row = r << 6; int e = -1;
    #pragma unroll
    for (int i = 0; i < E_NUM; i++)
      if (row >= offs[i] && row < offs[i + 1]) e = i;
    rg2e[r] = e;
  }
}

// ---------------- 2b) init padded row arrays ----------------
__global__ __launch_bounds__(256) void initrows_kernel(int* __restrict__ row_token) {
  int i = blockIdx.x * 256 + threadIdx.x;
  if (i < RPMAX) row_token[i] = -1;
}

// ---------------- 3) scatter (+ inverse map trow) ----------------
__global__ __launch_bounds__(256) void scatter_kernel(
    const int* __restrict__ topk_idx, const float* __restrict__ topk_w,
    const int* __restrict__ offp, int* __restrict__ cursor,
    int* __restrict__ row_token, int* __restrict__ trow)
{
  int t = blockIdx.x * 256 + threadIdx.x;
  if (t >= T_TOK) return;
  #pragma unroll
  for (int k = 0; k < TOPK; k++) {
    int e = topk_idx[t * 2 + k];
    int pos = atomicAdd(&cursor[e], 1);
    int row = offp[e] + pos;
    row_token[row] = t;
    trow[t * 2 + k] = row;
  }
}

// ---------------- 4) GU GEMM: LDS-staged 2-phase pipelined -------------------
// Tile 128 rows x 128 cols (g & u), 4 waves of 64x64, BK=32, KC=16 steps.
__global__ __launch_bounds__(256, 2) void gu9_kernel(
    const ushort_t* __restrict__ xgf, const ushort_t* __restrict__ xsf,
    const ushort_t* __restrict__ wgf, const ushort_t* __restrict__ wuf,
    const ushort_t* __restrict__ swgf, const ushort_t* __restrict__ swuf,
    ushort_t* __restrict__ interF, ushort_t* __restrict__ interS,
    const int* __restrict__ rt2e)
{
  const int KC = H_DIM / 32;   // 16
  int bid = blockIdx.x;
  int tid = threadIdx.x, w = tid >> 6, l = tid & 63;
  int wm = w >> 1, wn = w & 1;
  int fr = l & 15, g = l >> 4;

  const bf16x8 *AF, *BGF, *BUF;
  bf16x8* OP;
  int rg0, cg0, kkd0, KCd;

  if (bid < 16 * NRT128) {
    int cb = bid & 15, rt = bid >> 4;
    int e = rt2e[rt]; if (e < 0) return;
    rg0 = rt * 8;
    AF  = (const bf16x8*)xgf;
    BGF = (const bf16x8*)wgf;  BUF = (const bf16x8*)wuf;
    cg0 = e * (I_DIM >> 4) + cb * 8;
    KCd = I_DIM >> 5; kkd0 = cb * 4 + wn * 2;
    OP  = (bf16x8*)interF;
  } else {
    int b2 = bid - 16 * NRT128;
    int cb = b2 & 7, rt = b2 >> 3;
    rg0 = rt * 8;
    AF  = (const bf16x8*)xsf;
    BGF = (const bf16x8*)swgf; BUF = (const bf16x8*)swuf;
    cg0 = cb * 8;
    KCd = IS_DIM >> 5; kkd0 = cb * 4 + wn * 2;
    OP  = (bf16x8*)interS;
  }

  __shared__ ushort_t sm[6][4096];   // [0..1]=A dbuf, [2..3]=Bg, [4..5]=Bu

  const bf16x8* sa0 = AF  + (size_t)(rg0 + 2 * w)     * KC * 64 + l;
  const bf16x8* sa1 = AF  + (size_t)(rg0 + 2 * w + 1) * KC * 64 + l;
  const bf16x8* sg0 = BGF + (size_t)(cg0 + 2 * w)     * KC * 64 + l;
  const bf16x8* sg1 = BGF + (size_t)(cg0 + 2 * w + 1) * KC * 64 + l;
  const bf16x8* su0 = BUF + (size_t)(cg0 + 2 * w)     * KC * 64 + l;
  const bf16x8* su1 = BUF + (size_t)(cg0 + 2 * w + 1) * KC * 64 + l;
  int s0 = (2 * w) * 512, s1 = (2 * w + 1) * 512;

  f32x4 accg[4][4] = {}, accu[4][4] = {};

  auto stage = [&](int b, int kk) {
    gload16(sa0 + (size_t)kk * 64, &sm[0 + b][s0]);
    gload16(sa1 + (size_t)kk * 64, &sm[0 + b][s1]);
    gload16(sg0 + (size_t)kk * 64, &sm[2 + b][s0]);
    gload16(sg1 + (size_t)kk * 64, &sm[2 + b][s1]);
    gload16(su0 + (size_t)kk * 64, &sm[4 + b][s0]);
    gload16(su1 + (size_t)kk * 64, &sm[4 + b][s1]);
  };
  auto compute = [&](int b) {
    bf16x8 af[4], bg[4], bu[4];
    #pragma unroll
    for (int mi = 0; mi < 4; mi++)
      af[mi] = *(const bf16x8*)&sm[0 + b][(wm * 4 + mi) * 512 + l * 8];
    #pragma unroll
    for (int ni = 0; ni < 4; ni++) {
      bg[ni] = *(const bf16x8*)&sm[2 + b][(wn * 4 + ni) * 512 + l * 8];
      bu[ni] = *(const bf16x8*)&sm[4 + b][(wn * 4 + ni) * 512 + l * 8];
    }
    #pragma unroll
    for (int mi = 0; mi < 4; mi++)
      #pragma unroll
      for (int ni = 0; ni < 4; ni++) {
        accg[mi][ni] = __builtin_amdgcn_mfma_f32_16x16x32_bf16(af[mi], bg[ni], accg[mi][ni], 0, 0, 0);
        accu[mi][ni] = __builtin_amdgcn_mfma_f32_16x16x32_bf16(af[mi], bu[ni], accu[mi][ni], 0, 0, 0);
      }
  };

  stage(0, 0);
  __syncthreads();
  for (int kk = 0; kk < KC; kk += 2) {
    if (kk + 1 < KC) stage(1, kk + 1);
    compute(0);
    __syncthreads();
    if (kk + 2 < KC) stage(0, kk + 2);
    if (kk + 1 < KC) compute(1);
    __syncthreads();
  }

  // epilogue: silu(g)*u -> per-wave bounce (transpose to FM) -> global FM write
  ushort_t* bw = &sm[0][0] + w * (64 * 72);
  #pragma unroll
  for (int mi = 0; mi < 4; mi++)
    #pragma unroll
    for (int ni = 0; ni < 4; ni++)
      #pragma unroll
      for (int j = 0; j < 4; j++) {
        float gg = accg[mi][ni][j], uu = accu[mi][ni][j];
        float s = (gg / (1.f + expf(-gg))) * uu;
        bw[(mi * 16 + g * 4 + j) * 72 + ni * 16 + fr] = f2bf(s);
      }
  #pragma unroll
  for (int rgi = 0; rgi < 4; rgi++)
    #pragma unroll
    for (int kki = 0; kki < 2; kki++) {
      bf16x8 v = *(const bf16x8*)&bw[(rgi * 16 + (l & 15)) * 72 + kki * 32 + (l >> 4) * 8];
      OP[((size_t)(rg0 + wm * 4 + rgi) * KCd + kkd0 + kki) * 64 + l] = v;
    }
}

// ---------------- 5) down GEMM: LDS-staged 2-phase, no atomics ----------------
__global__ __launch_bounds__(128, 3) void down9_kernel(
    const ushort_t* __restrict__ interF, const ushort_t* __restrict__ interS,
    const ushort_t* __restrict__ wdf, const ushort_t* __restrict__ swdf,
    float* __restrict__ Dr, float* __restrict__ Ds,
    const int* __restrict__ rg2e)
{
  int bid = blockIdx.x;
  int tid = threadIdx.x, w = tid >> 6, l = tid & 63;
  int fr = l & 15, g = l >> 4;

  const bf16x8 *AF, *BF;
  float* DO;
  int rgA0, cg0, nk, row0, col0;

  if (bid < 4 * NRT64) {
    int cb = bid & 3, rt = bid >> 2;
    int e = rg2e[rt]; if (e < 0) return;
    AF = (const bf16x8*)interF; BF = (const bf16x8*)wdf;
    rgA0 = rt * 4; cg0 = e * (H_DIM >> 4) + cb * 8;
    nk = I_DIM >> 5;   // 64
    row0 = rt * 64; col0 = cb * 128;
    DO = Dr;
  } else {
    int b2 = bid - 4 * NRT64;
    int cb = b2 & 3, rt = b2 >> 2;
    AF = (const bf16x8*)interS; BF = (const bf16x8*)swdf;
    rgA0 = rt * 4; cg0 = cb * 8;
    nk = IS_DIM >> 5;  // 32
    row0 = rt * 64; col0 = cb * 128;
    DO = Ds;
  }

  __shared__ ushort_t sm[2][6144];   // 12 chunks (4 A + 8 B) x 2 buf = 24KB

  const bf16x8* sa0 = AF + ((size_t)(rgA0 + 2 * w)     * nk) * 64 + l;
  const bf16x8* sa1 = AF + ((size_t)(rgA0 + 2 * w + 1) * nk) * 64 + l;
  const bf16x8* sb0 = BF + ((size_t)(cg0 + 4 * w)      * nk) * 64 + l;
  const bf16x8* sb1 = BF + ((size_t)(cg0 + 4 * w + 1)  * nk) * 64 + l;
  const bf16x8* sb2 = BF + ((size_t)(cg0 + 4 * w + 2)  * nk) * 64 + l;
  const bf16x8* sb3 = BF + ((size_t)(cg0 + 4 * w + 3)  * nk) * 64 + l;

  f32x4 acc[4][4] = {};

  auto stage = [&](int b, int kk) {
    gload16(sa0 + (size_t)kk * 64, &sm[b][(2 * w) * 512]);
    gload16(sa1 + (size_t)kk * 64, &sm[b][(2 * w + 1) * 512]);
    gload16(sb0 + (size_t)kk * 64, &sm[b][(4 + 4 * w) * 512]);
    gload16(sb1 + (size_t)kk * 64, &sm[b][(5 + 4 * w) * 512]);
    gload16(sb2 + (size_t)kk * 64, &sm[b][(6 + 4 * w) * 512]);
    gload16(sb3 + (size_t)kk * 64, &sm[b][(7 + 4 * w) * 512]);
  };
  auto compute = [&](int b) {
    bf16x8 af[4], bf[4];
    #pragma unroll
    for (int mi = 0; mi < 4; mi++)
      af[mi] = *(const bf16x8*)&sm[b][mi * 512 + l * 8];
    #pragma unroll
    for (int ni = 0; ni < 4; ni++)
      bf[ni] = *(const bf16x8*)&sm[b][(4 + w * 4 + ni) * 512 + l * 8];
    #pragma unroll
    for (int mi = 0; mi < 4; mi++)
      #pragma unroll
      for (int ni = 0; ni < 4; ni++)
        acc[mi][ni] = __builtin_amdgcn_mfma_f32_16x16x32_bf16(af[mi], bf[ni], acc[mi][ni], 0, 0, 0);
  };

  stage(0, 0);
  __syncthreads();
  for (int kk = 0; kk < nk; kk += 2) {
    stage(1, kk + 1);
    compute(0);
    __syncthreads();
    if (kk + 2 < nk) stage(0, kk + 2);
    compute(1);
    __syncthreads();
  }

  #pragma unroll
  for (int mi = 0; mi < 4; mi++)
    #pragma unroll
    for (int ni = 0; ni < 4; ni++)
      #pragma unroll
      for (int j = 0; j < 4; j++)
        DO[(size_t)(row0 + mi * 16 + g * 4 + j) * H_DIM + col0 + w * 64 + ni * 16 + fr]
            = acc[mi][ni][j];
}

// ---------------- 6) combine: out[t] = w0*Dr[r0] + w1*Dr[r1] + Ds[t] ----------
__global__ __launch_bounds__(128) void combine_kernel(
    const float* __restrict__ Dr, const float* __restrict__ Ds,
    const int* __restrict__ trow, const float* __restrict__ topk_w,
    float* __restrict__ out)
{
  int t = blockIdx.x, c = threadIdx.x;
  int r0 = trow[t * 2], r1 = trow[t * 2 + 1];
  float w0 = topk_w[t * 2], w1 = topk_w[t * 2 + 1];
  float4 a = ((const float4*)(Dr + (size_t)r0 * H_DIM))[c];
  float4 b = ((const float4*)(Dr + (size_t)r1 * H_DIM))[c];
  float4 s = ((const float4*)(Ds + (size_t)t * H_DIM))[c];
  float4 r;
  r.x = w0 * a.x + w1 * b.x + s.x;
  r.y = w0 * a.y + w1 * b.y + s.y;
  r.z = w0 * a.z + w1 * b.z + s.z;
  r.w = w0 * a.w + w1 * b.w + s.w;
  ((float4*)(out + (size_t)t * H_DIM))[c] = r;
}

// ---------------- launch ----------------
extern "C" void kernel_launch(void* const* d_in, const int* in_sizes, int n_in,
                              void* d_out, int out_size, void* d_ws, size_t ws_size,
                              hipStream_t stream) {
  const float* x       = (const float*)d_in[0];
  const float* gate_w  = (const float*)d_in[1];
  const float* w_gate  = (const float*)d_in[2];
  const float* w_up    = (const float*)d_in[3];
  const float* w_down  = (const float*)d_in[4];
  const float* sw_gate = (const float*)d_in[5];
  const float* sw_up   = (const float*)d_in[6];
  const float* sw_down = (const float*)d_in[7];
  float* out = (float*)d_out;

  char* ws = (char*)d_ws;
  int*   counts    = (int*)ws;                      // 16
  int*   cursor    = (int*)(ws + 64);               // 16
  int*   offp      = (int*)(ws + 128);              // 17
  int*   rt2e      = (int*)(ws + 256);              // 48
  int*   rg2e      = (int*)(ws + 448);              // 96
  int*   topk_idx  = (int*)(ws + 832);              // 4096
  float* topk_w    = (float*)(ws + 17216);          // 4096
  int*   trow      = (int*)(ws + 33600);            // 4096
  int*   row_token = (int*)(ws + 49984);            // RPMAX
  size_t off = 49984 + (size_t)RPMAX * 4;
  off = (off + 255) & ~(size_t)255;
  float*    logits = (float*)(ws + off);    off += (size_t)T_TOK * E_NUM * 4;       // 128 KiB
  ushort_t* xgf  = (ushort_t*)(ws + off); off += (size_t)RPMAX * H_DIM * 2;         // 6 MiB
  ushort_t* xsf  = (ushort_t*)(ws + off); off += (size_t)T_TOK * H_DIM * 2;         // 2 MiB
  ushort_t* wgf  = (ushort_t*)(ws + off); off += (size_t)E_NUM * I_DIM * H_DIM * 2; // 32 MiB
  ushort_t* wuf  = (ushort_t*)(ws + off); off += (size_t)E_NUM * I_DIM * H_DIM * 2; // 32 MiB
  ushort_t* wdf  = (ushort_t*)(ws + off); off += (size_t)E_NUM * H_DIM * I_DIM * 2; // 32 MiB
  ushort_t* swgf = (ushort_t*)(ws + off); off += (size_t)IS_DIM * H_DIM * 2;        // 1 MiB
  ushort_t* swuf = (ushort_t*)(ws + off); off += (size_t)IS_DIM * H_DIM * 2;        // 1 MiB
  ushort_t* swdf = (ushort_t*)(ws + off); off += (size_t)H_DIM * IS_DIM * 2;        // 1 MiB
  ushort_t* interF = (ushort_t*)(ws + off); off += (size_t)RPMAX * I_DIM * 2;       // 24 MiB
  ushort_t* interS = (ushort_t*)(ws + off); off += (size_t)T_TOK * IS_DIM * 2;      // 4 MiB
  float*    Dr     = (float*)(ws + off);    off += (size_t)RPMAX * H_DIM * 4;       // 12 MiB
  float*    Ds     = (float*)(ws + off);    off += (size_t)T_TOK * H_DIM * 4;       // 4 MiB

  hipMemsetAsync(counts, 0, 64, stream);
  // gate split: logits GEMV -> per-token softmax/top2 + histogram
  logits_kernel<<<T_TOK / 16, 256, 0, stream>>>(x, gate_w, logits);
  topk_kernel<<<T_TOK / 256, 256, 0, stream>>>(logits, topk_idx, topk_w, counts);
  offsets_kernel<<<1, 128, 0, stream>>>(counts, offp, cursor, rt2e, rg2e);
  initrows_kernel<<<RPMAX / 256, 256, 0, stream>>>(row_token);
  scatter_kernel<<<(T_TOK + 255) / 256, 256, 0, stream>>>(topk_idx, topk_w, offp, cursor,
                                                          row_token, trow);
  // A-operands into FM bf16
  gatherA_kernel<4><<<RPMAX * H_DIM / 8 / 256, 256, 0, stream>>>(
      x, row_token, xgf, RPMAX * H_DIM / 8, H_DIM);
  gatherA_kernel<4><<<T_TOK * H_DIM / 8 / 256, 256, 0, stream>>>(
      x, nullptr, xsf, T_TOK * H_DIM / 8, H_DIM);
  // weights into FM bf16
  permw_kernel<4><<<4096, 256, 0, stream>>>(w_gate, wgf, E_NUM * I_DIM * H_DIM / 8);
  permw_kernel<4><<<4096, 256, 0, stream>>>(w_up,   wuf, E_NUM * I_DIM * H_DIM / 8);
  permw_kernel<6><<<4096, 256, 0, stream>>>(w_down, wdf, E_NUM * H_DIM * I_DIM / 8);
  permw_kernel<4><<<256, 256, 0, stream>>>(sw_gate, swgf, IS_DIM * H_DIM / 8);
  permw_kernel<4><<<256, 256, 0, stream>>>(sw_up,   swuf, IS_DIM * H_DIM / 8);
  permw_kernel<5><<<256, 256, 0, stream>>>(sw_down, swdf, H_DIM * IS_DIM / 8);

  // GU: routed (16 cb x 48 rt = 768) + shared (8 cb x 16 rt = 128)
  gu9_kernel<<<16 * NRT128 + 8 * 16, 256, 0, stream>>>(
      xgf, xsf, wgf, wuf, swgf, swuf, interF, interS, rt2e);
  // down: routed (4 cb x 96 rt = 384) + shared (4 cb x 32 rt = 128)
  down9_kernel<<<4 * NRT64 + 4 * 32, 128, 0, stream>>>(
      interF, interS, wdf, swdf, Dr, Ds, rg2e);
  // combine
  combine_kernel<<<T_TOK, 128, 0, stream>>>(Dr, Ds, trow, topk_w, out);
}

// Round 12
// 199.070 us; speedup vs baseline: 1.6532x; 1.1494x over previous
//
#include <hip/hip_runtime.h>
#include <hip/hip_bf16.h>
#include <math.h>

// ---------------- problem constants ----------------
#define T_TOK 2048
#define H_DIM 512
#define E_NUM 16
#define TOPK  2
#define I_DIM 2048
#define IS_DIM 1024
#define RPMAX 6144             // padded grouped rows (128-aligned per expert)
#define NRT128 (RPMAX / 128)   // 48
#define NRT64  (RPMAX / 64)    // 96

typedef __attribute__((ext_vector_type(8))) short bf16x8;
typedef __attribute__((ext_vector_type(4))) float f32x4;
typedef unsigned short ushort_t;

static __device__ __forceinline__ unsigned short f2bf(float f) {
  unsigned int u = __float_as_uint(f);
  unsigned int r = (u + 0x7fffu + ((u >> 16) & 1u)) >> 16;   // RNE
  return (unsigned short)r;
}

static __device__ __forceinline__ bf16x8 pack8(float4 a, float4 b) {
  bf16x8 v;
  v[0] = (short)f2bf(a.x); v[1] = (short)f2bf(a.y);
  v[2] = (short)f2bf(a.z); v[3] = (short)f2bf(a.w);
  v[4] = (short)f2bf(b.x); v[5] = (short)f2bf(b.y);
  v[6] = (short)f2bf(b.z); v[7] = (short)f2bf(b.w);
  return v;
}

// async global->LDS, 16B/lane: global src per-lane, LDS dst wave-uniform+lane*16
static __device__ __forceinline__ void gload16(const void* g, void* l) {
  __builtin_amdgcn_global_load_lds(
      (const __attribute__((address_space(1))) unsigned int*)g,
      (__attribute__((address_space(3))) unsigned int*)l, 16, 0, 0);
}

// ================= fragment-major (FM) layout =================
// M[R][K] row-major -> chunk c = rg*(K/32) + kk; lane l holds
// M[rg*16 + (l&15)][kk*32 + (l>>4)*8 .. +8] (one bf16x8, 16B).
// One chunk = ONE contiguous 1KB block.

// ------- weights fp32 row-major -> FM bf16 via LDS transpose (both coalesced) -
// One block per 16-row group; slabs of 512 K-elements. Phase 1: coalesced
// float4 reads, XOR-swizzled LDS store (col kq ^= r&7). Phase 2: FM-order
// LDS reads (2-way free by swizzle), convert, CONTIGUOUS 1KB global writes.
template <int LKC>
__global__ __launch_bounds__(256) void permw2_kernel(const float* __restrict__ s,
                                                     ushort_t* __restrict__ d) {
  const int KC = 1 << LKC;          // chunks per row-group
  const int K  = 32 << LKC;         // row length in floats
  const int NSLAB = KC / 16;
  __shared__ float ls[16 * 512];    // 32 KB
  int rg = blockIdx.x;
  int tid = threadIdx.x;
  for (int sl = 0; sl < NSLAB; sl++) {
    if (sl) __syncthreads();
    #pragma unroll
    for (int it = 0; it < 8; it++) {
      int i = tid + it * 256;       // 0..2047 float4 units
      int r = i >> 7, kq = i & 127;
      float4 v = *(const float4*)(s + (size_t)(rg * 16 + r) * K + sl * 512 + kq * 4);
      int kqs = kq ^ (r & 7);
      *(float4*)&ls[r * 512 + kqs * 4] = v;
    }
    __syncthreads();
    size_t obase = ((size_t)rg * KC + sl * 16) * 64;   // in 16B units
    #pragma unroll
    for (int it = 0; it < 4; it++) {
      int o = tid + it * 256;       // 0..1023
      int l = o & 63, kk = o >> 6;
      int r = l & 15, h = l >> 4;
      int p = kk * 8 + h * 2;
      int c = r & 7;
      float4 f0 = *(const float4*)&ls[r * 512 + ((p    ) ^ c) * 4];
      float4 f1 = *(const float4*)&ls[r * 512 + ((p + 1) ^ c) * 4];
      ((bf16x8*)d)[obase + o] = pack8(f0, f1);
    }
  }
}

// ---------------- x fp32 -> FM bf16 with optional token gather ----------------
template <int LKC>
__global__ __launch_bounds__(256) void gatherA_kernel(const float* __restrict__ x,
                                                      const int* __restrict__ row_token,
                                                      ushort_t* __restrict__ d,
                                                      int n8, int K) {
  const int KC = 1 << LKC;
  int i = blockIdx.x * 256 + threadIdx.x;
  int stride = gridDim.x * 256;
  for (; i < n8; i += stride) {
    int l  = i & 63;
    int fi = i >> 6;
    int kk = fi & (KC - 1);
    int rg = fi >> LKC;
    int row = rg * 16 + (l & 15);
    int tok = row_token ? row_token[row] : row;
    bf16x8 v = {};
    if (tok >= 0) {
      const float* p = x + (size_t)tok * K + kk * 32 + (l >> 4) * 8;
      v = pack8(*(const float4*)p, *(const float4*)(p + 4));
    }
    ((bf16x8*)d)[i] = v;
  }
}

// ---------------- 1a) logits GEMV: logits[t][e] = dot(x[t], gw[e]) ----------
__global__ __launch_bounds__(256) void logits_kernel(
    const float* __restrict__ x, const float* __restrict__ gw,
    float* __restrict__ logits)
{
  __shared__ float xs[16][516];
  int tid = threadIdx.x;
  int t0 = blockIdx.x * 16;
  for (int i = tid; i < 2048; i += 256) {   // 16 rows x 128 float4, coalesced
    int tt = i >> 7, q = i & 127;
    float4 v = ((const float4*)(x + (size_t)(t0 + tt) * H_DIM))[q];
    *(float4*)&xs[tt][q * 4] = v;
  }
  __syncthreads();
  int e = tid >> 4, tt = tid & 15;
  const float* gr = gw + (size_t)e * H_DIM;
  const float* xr = &xs[tt][0];
  int kbase = (blockIdx.x & 7) << 6;        // stagger L2 hotspot
  float acc = 0.f;
  #pragma unroll 8
  for (int kk = 0; kk < H_DIM; kk += 4) {
    int k = (kbase + kk) & (H_DIM - 1);
    float4 b = *(const float4*)(gr + k);
    float4 a = *(const float4*)(xr + k);
    acc += a.x * b.x + a.y * b.y + a.z * b.z + a.w * b.w;
  }
  logits[(size_t)(t0 + tt) * E_NUM + e] = acc;
}

// ---------------- 1b) softmax + top2 + histogram counts ----------------
__global__ __launch_bounds__(256) void topk_kernel(
    const float* __restrict__ logits,
    int* __restrict__ topk_idx, float* __restrict__ topk_w, int* __restrict__ counts)
{
  __shared__ int hist[E_NUM];
  int tid = threadIdx.x;
  if (tid < E_NUM) hist[tid] = 0;
  __syncthreads();
  int t = blockIdx.x * 256 + tid;
  float lg[E_NUM];
  #pragma unroll
  for (int i = 0; i < 4; i++) {
    float4 v = ((const float4*)(logits + (size_t)t * E_NUM))[i];
    lg[i * 4] = v.x; lg[i * 4 + 1] = v.y; lg[i * 4 + 2] = v.z; lg[i * 4 + 3] = v.w;
  }
  float mx = lg[0];
  #pragma unroll
  for (int i = 1; i < E_NUM; i++) mx = fmaxf(mx, lg[i]);
  float sc[E_NUM];
  float sum = 0.f;
  #pragma unroll
  for (int i = 0; i < E_NUM; i++) { sc[i] = expf(lg[i] - mx); sum += sc[i]; }
  float inv = 1.f / sum;
  float m1 = -1.f, m2 = -1.f; int i1 = 0, i2 = 0;
  #pragma unroll
  for (int i = 0; i < E_NUM; i++) {
    float s = sc[i] * inv;
    if (s > m1)      { m2 = m1; i2 = i1; m1 = s; i1 = i; }
    else if (s > m2) { m2 = s; i2 = i; }
  }
  topk_idx[t * 2] = i1; topk_idx[t * 2 + 1] = i2;
  topk_w[t * 2] = m1;  topk_w[t * 2 + 1] = m2;
  atomicAdd(&hist[i1], 1);
  atomicAdd(&hist[i2], 1);
  __syncthreads();
  if (tid < E_NUM) atomicAdd(&counts[tid], hist[tid]);
}

// ---------------- 2) 128-aligned padded scan + tile->expert maps (parallel) ---
__global__ void offsets_kernel(const int* __restrict__ counts,
                               int* __restrict__ offp, int* __restrict__ cursor,
                               int* __restrict__ rt2e, int* __restrict__ rg2e)
{
  __shared__ int offs[E_NUM + 1];
  int tid = threadIdx.x;
  if (tid == 0) {
    int acc = 0;
    #pragma unroll
    for (int e = 0; e < E_NUM; e++) {
      offs[e] = acc; offp[e] = acc;
      acc += (counts[e] + 127) & ~127;
    }
    offs[E_NUM] = acc; offp[E_NUM] = acc;
  }
  if (tid < E_NUM) cursor[tid] = 0;
  __syncthreads();
  for (int r = tid; r < NRT128; r += 128) {
    int row = r << 7; int e = -1;
    #pragma unroll
    for (int i = 0; i < E_NUM; i++)
      if (row >= offs[i] && row < offs[i + 1]) e = i;
    rt2e[r] = e;
  }
  for (int r = tid; r < NRT64; r += 128) {
    int row = r << 6; int e = -1;
    #pragma unroll
    for (int i = 0; i < E_NUM; i++)
      if (row >= offs[i] && row < offs[i + 1]) e = i;
    rg2e[r] = e;
  }
}

// ---------------- 2b) init padded row arrays ----------------
__global__ __launch_bounds__(256) void initrows_kernel(int* __restrict__ row_token) {
  int i = blockIdx.x * 256 + threadIdx.x;
  if (i < RPMAX) row_token[i] = -1;
}

// ---------------- 3) scatter (+ inverse map trow) ----------------
__global__ __launch_bounds__(256) void scatter_kernel(
    const int* __restrict__ topk_idx, const float* __restrict__ topk_w,
    const int* __restrict__ offp, int* __restrict__ cursor,
    int* __restrict__ row_token, int* __restrict__ trow)
{
  int t = blockIdx.x * 256 + threadIdx.x;
  if (t >= T_TOK) return;
  #pragma unroll
  for (int k = 0; k < TOPK; k++) {
    int e = topk_idx[t * 2 + k];
    int pos = atomicAdd(&cursor[e], 1);
    int row = offp[e] + pos;
    row_token[row] = t;
    trow[t * 2 + k] = row;
  }
}

// ---------------- 4) GU GEMM: LDS-staged 2-phase pipelined -------------------
// Tile 128 rows x 128 cols (g & u), 4 waves of 64x64, BK=32, KC=16 steps.
__global__ __launch_bounds__(256, 2) void gu9_kernel(
    const ushort_t* __restrict__ xgf, const ushort_t* __restrict__ xsf,
    const ushort_t* __restrict__ wgf, const ushort_t* __restrict__ wuf,
    const ushort_t* __restrict__ swgf, const ushort_t* __restrict__ swuf,
    ushort_t* __restrict__ interF, ushort_t* __restrict__ interS,
    const int* __restrict__ rt2e)
{
  const int KC = H_DIM / 32;   // 16
  int bid = blockIdx.x;
  int tid = threadIdx.x, w = tid >> 6, l = tid & 63;
  int wm = w >> 1, wn = w & 1;
  int fr = l & 15, g = l >> 4;

  const bf16x8 *AF, *BGF, *BUF;
  bf16x8* OP;
  int rg0, cg0, kkd0, KCd;

  if (bid < 16 * NRT128) {
    int cb = bid & 15, rt = bid >> 4;
    int e = rt2e[rt]; if (e < 0) return;
    rg0 = rt * 8;
    AF  = (const bf16x8*)xgf;
    BGF = (const bf16x8*)wgf;  BUF = (const bf16x8*)wuf;
    cg0 = e * (I_DIM >> 4) + cb * 8;
    KCd = I_DIM >> 5; kkd0 = cb * 4 + wn * 2;
    OP  = (bf16x8*)interF;
  } else {
    int b2 = bid - 16 * NRT128;
    int cb = b2 & 7, rt = b2 >> 3;
    rg0 = rt * 8;
    AF  = (const bf16x8*)xsf;
    BGF = (const bf16x8*)swgf; BUF = (const bf16x8*)swuf;
    cg0 = cb * 8;
    KCd = IS_DIM >> 5; kkd0 = cb * 4 + wn * 2;
    OP  = (bf16x8*)interS;
  }

  __shared__ ushort_t sm[6][4096];   // [0..1]=A dbuf, [2..3]=Bg, [4..5]=Bu

  const bf16x8* sa0 = AF  + (size_t)(rg0 + 2 * w)     * KC * 64 + l;
  const bf16x8* sa1 = AF  + (size_t)(rg0 + 2 * w + 1) * KC * 64 + l;
  const bf16x8* sg0 = BGF + (size_t)(cg0 + 2 * w)     * KC * 64 + l;
  const bf16x8* sg1 = BGF + (size_t)(cg0 + 2 * w + 1) * KC * 64 + l;
  const bf16x8* su0 = BUF + (size_t)(cg0 + 2 * w)     * KC * 64 + l;
  const bf16x8* su1 = BUF + (size_t)(cg0 + 2 * w + 1) * KC * 64 + l;
  int s0 = (2 * w) * 512, s1 = (2 * w + 1) * 512;

  f32x4 accg[4][4] = {}, accu[4][4] = {};

  auto stage = [&](int b, int kk) {
    gload16(sa0 + (size_t)kk * 64, &sm[0 + b][s0]);
    gload16(sa1 + (size_t)kk * 64, &sm[0 + b][s1]);
    gload16(sg0 + (size_t)kk * 64, &sm[2 + b][s0]);
    gload16(sg1 + (size_t)kk * 64, &sm[2 + b][s1]);
    gload16(su0 + (size_t)kk * 64, &sm[4 + b][s0]);
    gload16(su1 + (size_t)kk * 64, &sm[4 + b][s1]);
  };
  auto compute = [&](int b) {
    bf16x8 af[4], bg[4], bu[4];
    #pragma unroll
    for (int mi = 0; mi < 4; mi++)
      af[mi] = *(const bf16x8*)&sm[0 + b][(wm * 4 + mi) * 512 + l * 8];
    #pragma unroll
    for (int ni = 0; ni < 4; ni++) {
      bg[ni] = *(const bf16x8*)&sm[2 + b][(wn * 4 + ni) * 512 + l * 8];
      bu[ni] = *(const bf16x8*)&sm[4 + b][(wn * 4 + ni) * 512 + l * 8];
    }
    #pragma unroll
    for (int mi = 0; mi < 4; mi++)
      #pragma unroll
      for (int ni = 0; ni < 4; ni++) {
        accg[mi][ni] = __builtin_amdgcn_mfma_f32_16x16x32_bf16(af[mi], bg[ni], accg[mi][ni], 0, 0, 0);
        accu[mi][ni] = __builtin_amdgcn_mfma_f32_16x16x32_bf16(af[mi], bu[ni], accu[mi][ni], 0, 0, 0);
      }
  };

  stage(0, 0);
  __syncthreads();
  for (int kk = 0; kk < KC; kk += 2) {
    if (kk + 1 < KC) stage(1, kk + 1);
    compute(0);
    __syncthreads();
    if (kk + 2 < KC) stage(0, kk + 2);
    if (kk + 1 < KC) compute(1);
    __syncthreads();
  }

  // epilogue: silu(g)*u -> per-wave bounce (transpose to FM) -> global FM write
  ushort_t* bw = &sm[0][0] + w * (64 * 72);
  #pragma unroll
  for (int mi = 0; mi < 4; mi++)
    #pragma unroll
    for (int ni = 0; ni < 4; ni++)
      #pragma unroll
      for (int j = 0; j < 4; j++) {
        float gg = accg[mi][ni][j], uu = accu[mi][ni][j];
        float s = (gg / (1.f + expf(-gg))) * uu;
        bw[(mi * 16 + g * 4 + j) * 72 + ni * 16 + fr] = f2bf(s);
      }
  #pragma unroll
  for (int rgi = 0; rgi < 4; rgi++)
    #pragma unroll
    for (int kki = 0; kki < 2; kki++) {
      bf16x8 v = *(const bf16x8*)&bw[(rgi * 16 + (l & 15)) * 72 + kki * 32 + (l >> 4) * 8];
      OP[((size_t)(rg0 + wm * 4 + rgi) * KCd + kkd0 + kki) * 64 + l] = v;
    }
}

// ---------------- 5) down GEMM: LDS-staged 2-phase, no atomics ----------------
__global__ __launch_bounds__(128, 3) void down9_kernel(
    const ushort_t* __restrict__ interF, const ushort_t* __restrict__ interS,
    const ushort_t* __restrict__ wdf, const ushort_t* __restrict__ swdf,
    float* __restrict__ Dr, float* __restrict__ Ds,
    const int* __restrict__ rg2e)
{
  int bid = blockIdx.x;
  int tid = threadIdx.x, w = tid >> 6, l = tid & 63;
  int fr = l & 15, g = l >> 4;

  const bf16x8 *AF, *BF;
  float* DO;
  int rgA0, cg0, nk, row0, col0;

  if (bid < 4 * NRT64) {
    int cb = bid & 3, rt = bid >> 2;
    int e = rg2e[rt]; if (e < 0) return;
    AF = (const bf16x8*)interF; BF = (const bf16x8*)wdf;
    rgA0 = rt * 4; cg0 = e * (H_DIM >> 4) + cb * 8;
    nk = I_DIM >> 5;   // 64
    row0 = rt * 64; col0 = cb * 128;
    DO = Dr;
  } else {
    int b2 = bid - 4 * NRT64;
    int cb = b2 & 3, rt = b2 >> 2;
    AF = (const bf16x8*)interS; BF = (const bf16x8*)swdf;
    rgA0 = rt * 4; cg0 = cb * 8;
    nk = IS_DIM >> 5;  // 32
    row0 = rt * 64; col0 = cb * 128;
    DO = Ds;
  }

  __shared__ ushort_t sm[2][6144];   // 12 chunks (4 A + 8 B) x 2 buf = 24KB

  const bf16x8* sa0 = AF + ((size_t)(rgA0 + 2 * w)     * nk) * 64 + l;
  const bf16x8* sa1 = AF + ((size_t)(rgA0 + 2 * w + 1) * nk) * 64 + l;
  const bf16x8* sb0 = BF + ((size_t)(cg0 + 4 * w)      * nk) * 64 + l;
  const bf16x8* sb1 = BF + ((size_t)(cg0 + 4 * w + 1)  * nk) * 64 + l;
  const bf16x8* sb2 = BF + ((size_t)(cg0 + 4 * w + 2)  * nk) * 64 + l;
  const bf16x8* sb3 = BF + ((size_t)(cg0 + 4 * w + 3)  * nk) * 64 + l;

  f32x4 acc[4][4] = {};

  auto stage = [&](int b, int kk) {
    gload16(sa0 + (size_t)kk * 64, &sm[b][(2 * w) * 512]);
    gload16(sa1 + (size_t)kk * 64, &sm[b][(2 * w + 1) * 512]);
    gload16(sb0 + (size_t)kk * 64, &sm[b][(4 + 4 * w) * 512]);
    gload16(sb1 + (size_t)kk * 64, &sm[b][(5 + 4 * w) * 512]);
    gload16(sb2 + (size_t)kk * 64, &sm[b][(6 + 4 * w) * 512]);
    gload16(sb3 + (size_t)kk * 64, &sm[b][(7 + 4 * w) * 512]);
  };
  auto compute = [&](int b) {
    bf16x8 af[4], bf[4];
    #pragma unroll
    for (int mi = 0; mi < 4; mi++)
      af[mi] = *(const bf16x8*)&sm[b][mi * 512 + l * 8];
    #pragma unroll
    for (int ni = 0; ni < 4; ni++)
      bf[ni] = *(const bf16x8*)&sm[b][(4 + w * 4 + ni) * 512 + l * 8];
    #pragma unroll
    for (int mi = 0; mi < 4; mi++)
      #pragma unroll
      for (int ni = 0; ni < 4; ni++)
        acc[mi][ni] = __builtin_amdgcn_mfma_f32_16x16x32_bf16(af[mi], bf[ni], acc[mi][ni], 0, 0, 0);
  };

  stage(0, 0);
  __syncthreads();
  for (int kk = 0; kk < nk; kk += 2) {
    stage(1, kk + 1);
    compute(0);
    __syncthreads();
    if (kk + 2 < nk) stage(0, kk + 2);
    compute(1);
    __syncthreads();
  }

  #pragma unroll
  for (int mi = 0; mi < 4; mi++)
    #pragma unroll
    for (int ni = 0; ni < 4; ni++)
      #pragma unroll
      for (int j = 0; j < 4; j++)
        DO[(size_t)(row0 + mi * 16 + g * 4 + j) * H_DIM + col0 + w * 64 + ni * 16 + fr]
            = acc[mi][ni][j];
}

// ---------------- 6) combine: out[t] = w0*Dr[r0] + w1*Dr[r1] + Ds[t] ----------
__global__ __launch_bounds__(128) void combine_kernel(
    const float* __restrict__ Dr, const float* __restrict__ Ds,
    const int* __restrict__ trow, const float* __restrict__ topk_w,
    float* __restrict__ out)
{
  int t = blockIdx.x, c = threadIdx.x;
  int r0 = trow[t * 2], r1 = trow[t * 2 + 1];
  float w0 = topk_w[t * 2], w1 = topk_w[t * 2 + 1];
  float4 a = ((const float4*)(Dr + (size_t)r0 * H_DIM))[c];
  float4 b = ((const float4*)(Dr + (size_t)r1 * H_DIM))[c];
  float4 s = ((const float4*)(Ds + (size_t)t * H_DIM))[c];
  float4 r;
  r.x = w0 * a.x + w1 * b.x + s.x;
  r.y = w0 * a.y + w1 * b.y + s.y;
  r.z = w0 * a.z + w1 * b.z + s.z;
  r.w = w0 * a.w + w1 * b.w + s.w;
  ((float4*)(out + (size_t)t * H_DIM))[c] = r;
}

// ---------------- launch ----------------
extern "C" void kernel_launch(void* const* d_in, const int* in_sizes, int n_in,
                              void* d_out, int out_size, void* d_ws, size_t ws_size,
                              hipStream_t stream) {
  const float* x       = (const float*)d_in[0];
  const float* gate_w  = (const float*)d_in[1];
  const float* w_gate  = (const float*)d_in[2];
  const float* w_up    = (const float*)d_in[3];
  const float* w_down  = (const float*)d_in[4];
  const float* sw_gate = (const float*)d_in[5];
  const float* sw_up   = (const float*)d_in[6];
  const float* sw_down = (const float*)d_in[7];
  float* out = (float*)d_out;

  char* ws = (char*)d_ws;
  int*   counts    = (int*)ws;                      // 16
  int*   cursor    = (int*)(ws + 64);               // 16
  int*   offp      = (int*)(ws + 128);              // 17
  int*   rt2e      = (int*)(ws + 256);              // 48
  int*   rg2e      = (int*)(ws + 448);              // 96
  int*   topk_idx  = (int*)(ws + 832);              // 4096
  float* topk_w    = (float*)(ws + 17216);          // 4096
  int*   trow      = (int*)(ws + 33600);            // 4096
  int*   row_token = (int*)(ws + 49984);            // RPMAX
  size_t off = 49984 + (size_t)RPMAX * 4;
  off = (off + 255) & ~(size_t)255;
  float*    logits = (float*)(ws + off);    off += (size_t)T_TOK * E_NUM * 4;       // 128 KiB
  ushort_t* xgf  = (ushort_t*)(ws + off); off += (size_t)RPMAX * H_DIM * 2;         // 6 MiB
  ushort_t* xsf  = (ushort_t*)(ws + off); off += (size_t)T_TOK * H_DIM * 2;         // 2 MiB
  ushort_t* wgf  = (ushort_t*)(ws + off); off += (size_t)E_NUM * I_DIM * H_DIM * 2; // 32 MiB
  ushort_t* wuf  = (ushort_t*)(ws + off); off += (size_t)E_NUM * I_DIM * H_DIM * 2; // 32 MiB
  ushort_t* wdf  = (ushort_t*)(ws + off); off += (size_t)E_NUM * H_DIM * I_DIM * 2; // 32 MiB
  ushort_t* swgf = (ushort_t*)(ws + off); off += (size_t)IS_DIM * H_DIM * 2;        // 1 MiB
  ushort_t* swuf = (ushort_t*)(ws + off); off += (size_t)IS_DIM * H_DIM * 2;        // 1 MiB
  ushort_t* swdf = (ushort_t*)(ws + off); off += (size_t)H_DIM * IS_DIM * 2;        // 1 MiB
  ushort_t* interF = (ushort_t*)(ws + off); off += (size_t)RPMAX * I_DIM * 2;       // 24 MiB
  ushort_t* interS = (ushort_t*)(ws + off); off += (size_t)T_TOK * IS_DIM * 2;      // 4 MiB
  float*    Dr     = (float*)(ws + off);    off += (size_t)RPMAX * H_DIM * 4;       // 12 MiB
  float*    Ds     = (float*)(ws + off);    off += (size_t)T_TOK * H_DIM * 4;       // 4 MiB

  hipMemsetAsync(counts, 0, 64, stream);
  // gate split: logits GEMV -> per-token softmax/top2 + histogram
  logits_kernel<<<T_TOK / 16, 256, 0, stream>>>(x, gate_w, logits);
  topk_kernel<<<T_TOK / 256, 256, 0, stream>>>(logits, topk_idx, topk_w, counts);
  offsets_kernel<<<1, 128, 0, stream>>>(counts, offp, cursor, rt2e, rg2e);
  initrows_kernel<<<RPMAX / 256, 256, 0, stream>>>(row_token);
  scatter_kernel<<<(T_TOK + 255) / 256, 256, 0, stream>>>(topk_idx, topk_w, offp, cursor,
                                                          row_token, trow);
  // A-operands into FM bf16
  gatherA_kernel<4><<<RPMAX * H_DIM / 8 / 256, 256, 0, stream>>>(
      x, row_token, xgf, RPMAX * H_DIM / 8, H_DIM);
  gatherA_kernel<4><<<T_TOK * H_DIM / 8 / 256, 256, 0, stream>>>(
      x, nullptr, xsf, T_TOK * H_DIM / 8, H_DIM);
  // weights into FM bf16 (LDS-transposed: coalesced reads AND writes)
  permw2_kernel<4><<<E_NUM * I_DIM / 16, 256, 0, stream>>>(w_gate, wgf);
  permw2_kernel<4><<<E_NUM * I_DIM / 16, 256, 0, stream>>>(w_up,   wuf);
  permw2_kernel<6><<<E_NUM * H_DIM / 16, 256, 0, stream>>>(w_down, wdf);
  permw2_kernel<4><<<IS_DIM / 16, 256, 0, stream>>>(sw_gate, swgf);
  permw2_kernel<4><<<IS_DIM / 16, 256, 0, stream>>>(sw_up,   swuf);
  permw2_kernel<5><<<H_DIM / 16, 256, 0, stream>>>(sw_down, swdf);

  // GU: routed (16 cb x 48 rt = 768) + shared (8 cb x 16 rt = 128)
  gu9_kernel<<<16 * NRT128 + 8 * 16, 256, 0, stream>>>(
      xgf, xsf, wgf, wuf, swgf, swuf, interF, interS, rt2e);
  // down: routed (4 cb x 96 rt = 384) + shared (4 cb x 32 rt = 128)
  down9_kernel<<<4 * NRT64 + 4 * 32, 128, 0, stream>>>(
      interF, interS, wdf, swdf, Dr, Ds, rg2e);
  // combine
  combine_kernel<<<T_TOK, 128, 0, stream>>>(Dr, Ds, trow, topk_w, out);
}

// Round 13
// 193.674 us; speedup vs baseline: 1.6992x; 1.0279x over previous
//
#include <hip/hip_runtime.h>
#include <hip/hip_bf16.h>
#include <math.h>

// ---------------- problem constants ----------------
#define T_TOK 2048
#define H_DIM 512
#define E_NUM 16
#define TOPK  2
#define I_DIM 2048
#define IS_DIM 1024
#define RPMAX 6144             // padded grouped rows (128-aligned per expert)
#define NRT128 (RPMAX / 128)   // 48
#define NRT64  (RPMAX / 64)    // 96

typedef __attribute__((ext_vector_type(8))) short bf16x8;
typedef __attribute__((ext_vector_type(4))) float f32x4;
typedef unsigned short ushort_t;

static __device__ __forceinline__ unsigned short f2bf(float f) {
  unsigned int u = __float_as_uint(f);
  unsigned int r = (u + 0x7fffu + ((u >> 16) & 1u)) >> 16;   // RNE
  return (unsigned short)r;
}

static __device__ __forceinline__ bf16x8 pack8(float4 a, float4 b) {
  bf16x8 v;
  v[0] = (short)f2bf(a.x); v[1] = (short)f2bf(a.y);
  v[2] = (short)f2bf(a.z); v[3] = (short)f2bf(a.w);
  v[4] = (short)f2bf(b.x); v[5] = (short)f2bf(b.y);
  v[6] = (short)f2bf(b.z); v[7] = (short)f2bf(b.w);
  return v;
}

// async global->LDS, 16B/lane: global src per-lane, LDS dst wave-uniform+lane*16
static __device__ __forceinline__ void gload16(const void* g, void* l) {
  __builtin_amdgcn_global_load_lds(
      (const __attribute__((address_space(1))) unsigned int*)g,
      (__attribute__((address_space(3))) unsigned int*)l, 16, 0, 0);
}

// ================= fragment-major (FM) layout =================
// M[R][K] row-major -> chunk c = rg*(K/32) + kk; lane l holds
// M[rg*16 + (l&15)][kk*32 + (l>>4)*8 .. +8] (one bf16x8, 16B).
// One chunk = ONE contiguous 1KB block.

// ------- weights fp32 row-major -> FM bf16 via LDS transpose (both coalesced) -
template <int LKC>
__global__ __launch_bounds__(256) void permw2_kernel(const float* __restrict__ s,
                                                     ushort_t* __restrict__ d) {
  const int KC = 1 << LKC;          // chunks per row-group
  const int K  = 32 << LKC;         // row length in floats
  const int NSLAB = KC / 16;
  __shared__ float ls[16 * 512];    // 32 KB
  int rg = blockIdx.x;
  int tid = threadIdx.x;
  for (int sl = 0; sl < NSLAB; sl++) {
    if (sl) __syncthreads();
    #pragma unroll
    for (int it = 0; it < 8; it++) {
      int i = tid + it * 256;       // 0..2047 float4 units
      int r = i >> 7, kq = i & 127;
      float4 v = *(const float4*)(s + (size_t)(rg * 16 + r) * K + sl * 512 + kq * 4);
      int kqs = kq ^ (r & 7);
      *(float4*)&ls[r * 512 + kqs * 4] = v;
    }
    __syncthreads();
    size_t obase = ((size_t)rg * KC + sl * 16) * 64;   // in 16B units
    #pragma unroll
    for (int it = 0; it < 4; it++) {
      int o = tid + it * 256;       // 0..1023
      int l = o & 63, kk = o >> 6;
      int r = l & 15, h = l >> 4;
      int p = kk * 8 + h * 2;
      int c = r & 7;
      float4 f0 = *(const float4*)&ls[r * 512 + ((p    ) ^ c) * 4];
      float4 f1 = *(const float4*)&ls[r * 512 + ((p + 1) ^ c) * 4];
      ((bf16x8*)d)[obase + o] = pack8(f0, f1);
    }
  }
}

// ---------------- x fp32 -> FM bf16 with optional token gather ----------------
template <int LKC>
__global__ __launch_bounds__(256) void gatherA_kernel(const float* __restrict__ x,
                                                      const int* __restrict__ row_token,
                                                      ushort_t* __restrict__ d,
                                                      int n8, int K) {
  const int KC = 1 << LKC;
  int i = blockIdx.x * 256 + threadIdx.x;
  int stride = gridDim.x * 256;
  for (; i < n8; i += stride) {
    int l  = i & 63;
    int fi = i >> 6;
    int kk = fi & (KC - 1);
    int rg = fi >> LKC;
    int row = rg * 16 + (l & 15);
    int tok = row_token ? row_token[row] : row;
    bf16x8 v = {};
    if (tok >= 0) {
      const float* p = x + (size_t)tok * K + kk * 32 + (l >> 4) * 8;
      v = pack8(*(const float4*)p, *(const float4*)(p + 4));
    }
    ((bf16x8*)d)[i] = v;
  }
}

// ---------------- 1a) logits GEMV: logits[t][e] = dot(x[t], gw[e]) ----------
__global__ __launch_bounds__(256) void logits_kernel(
    const float* __restrict__ x, const float* __restrict__ gw,
    float* __restrict__ logits)
{
  __shared__ float xs[16][516];
  int tid = threadIdx.x;
  int t0 = blockIdx.x * 16;
  for (int i = tid; i < 2048; i += 256) {   // 16 rows x 128 float4, coalesced
    int tt = i >> 7, q = i & 127;
    float4 v = ((const float4*)(x + (size_t)(t0 + tt) * H_DIM))[q];
    *(float4*)&xs[tt][q * 4] = v;
  }
  __syncthreads();
  int e = tid >> 4, tt = tid & 15;
  const float* gr = gw + (size_t)e * H_DIM;
  const float* xr = &xs[tt][0];
  int kbase = (blockIdx.x & 7) << 6;        // stagger L2 hotspot
  float acc = 0.f;
  #pragma unroll 8
  for (int kk = 0; kk < H_DIM; kk += 4) {
    int k = (kbase + kk) & (H_DIM - 1);
    float4 b = *(const float4*)(gr + k);
    float4 a = *(const float4*)(xr + k);
    acc += a.x * b.x + a.y * b.y + a.z * b.z + a.w * b.w;
  }
  logits[(size_t)(t0 + tt) * E_NUM + e] = acc;
}

// ---------------- 1b) softmax + top2 + histogram counts ----------------
__global__ __launch_bounds__(256) void topk_kernel(
    const float* __restrict__ logits,
    int* __restrict__ topk_idx, float* __restrict__ topk_w, int* __restrict__ counts)
{
  __shared__ int hist[E_NUM];
  int tid = threadIdx.x;
  if (tid < E_NUM) hist[tid] = 0;
  __syncthreads();
  int t = blockIdx.x * 256 + tid;
  float lg[E_NUM];
  #pragma unroll
  for (int i = 0; i < 4; i++) {
    float4 v = ((const float4*)(logits + (size_t)t * E_NUM))[i];
    lg[i * 4] = v.x; lg[i * 4 + 1] = v.y; lg[i * 4 + 2] = v.z; lg[i * 4 + 3] = v.w;
  }
  float mx = lg[0];
  #pragma unroll
  for (int i = 1; i < E_NUM; i++) mx = fmaxf(mx, lg[i]);
  float sc[E_NUM];
  float sum = 0.f;
  #pragma unroll
  for (int i = 0; i < E_NUM; i++) { sc[i] = expf(lg[i] - mx); sum += sc[i]; }
  float inv = 1.f / sum;
  float m1 = -1.f, m2 = -1.f; int i1 = 0, i2 = 0;
  #pragma unroll
  for (int i = 0; i < E_NUM; i++) {
    float s = sc[i] * inv;
    if (s > m1)      { m2 = m1; i2 = i1; m1 = s; i1 = i; }
    else if (s > m2) { m2 = s; i2 = i; }
  }
  topk_idx[t * 2] = i1; topk_idx[t * 2 + 1] = i2;
  topk_w[t * 2] = m1;  topk_w[t * 2 + 1] = m2;
  atomicAdd(&hist[i1], 1);
  atomicAdd(&hist[i2], 1);
  __syncthreads();
  if (tid < E_NUM) atomicAdd(&counts[tid], hist[tid]);
}

// ---------------- 2) 128-aligned padded scan + tile->expert maps (parallel) ---
__global__ void offsets_kernel(const int* __restrict__ counts,
                               int* __restrict__ offp, int* __restrict__ cursor,
                               int* __restrict__ rt2e, int* __restrict__ rg2e)
{
  __shared__ int offs[E_NUM + 1];
  int tid = threadIdx.x;
  if (tid == 0) {
    int acc = 0;
    #pragma unroll
    for (int e = 0; e < E_NUM; e++) {
      offs[e] = acc; offp[e] = acc;
      acc += (counts[e] + 127) & ~127;
    }
    offs[E_NUM] = acc; offp[E_NUM] = acc;
  }
  if (tid < E_NUM) cursor[tid] = 0;
  __syncthreads();
  for (int r = tid; r < NRT128; r += 128) {
    int row = r << 7; int e = -1;
    #pragma unroll
    for (int i = 0; i < E_NUM; i++)
      if (row >= offs[i] && row < offs[i + 1]) e = i;
    rt2e[r] = e;
  }
  for (int r = tid; r < NRT64; r += 128) {
    int row = r << 6; int e = -1;
    #pragma unroll
    for (int i = 0; i < E_NUM; i++)
      if (row >= offs[i] && row < offs[i + 1]) e = i;
    rg2e[r] = e;
  }
}

// ---------------- 2b) init padded row arrays ----------------
__global__ __launch_bounds__(256) void initrows_kernel(int* __restrict__ row_token) {
  int i = blockIdx.x * 256 + threadIdx.x;
  if (i < RPMAX) row_token[i] = -1;
}

// ---------------- 3) scatter (+ inverse map trow) ----------------
__global__ __launch_bounds__(256) void scatter_kernel(
    const int* __restrict__ topk_idx, const float* __restrict__ topk_w,
    const int* __restrict__ offp, int* __restrict__ cursor,
    int* __restrict__ row_token, int* __restrict__ trow)
{
  int t = blockIdx.x * 256 + threadIdx.x;
  if (t >= T_TOK) return;
  #pragma unroll
  for (int k = 0; k < TOPK; k++) {
    int e = topk_idx[t * 2 + k];
    int pos = atomicAdd(&cursor[e], 1);
    int row = offp[e] + pos;
    row_token[row] = t;
    trow[t * 2 + k] = row;
  }
}

// ---------------- 4) GU GEMM: 3-deep pipeline, counted vmcnt, raw barriers ----
// Tile 128 rows x 128 cols (g & u), 4 waves of 64x64, BK=32, KC=16 steps.
// LDS 72KB: 3 buffers x {A 8KB, Bg 8KB, Bu 8KB}. Loads never drain to 0.
__global__ __launch_bounds__(256, 2) void gu10_kernel(
    const ushort_t* __restrict__ xgf, const ushort_t* __restrict__ xsf,
    const ushort_t* __restrict__ wgf, const ushort_t* __restrict__ wuf,
    const ushort_t* __restrict__ swgf, const ushort_t* __restrict__ swuf,
    ushort_t* __restrict__ interF, ushort_t* __restrict__ interS,
    const int* __restrict__ rt2e)
{
  const int KC = H_DIM / 32;   // 16
  int bid = blockIdx.x;
  int tid = threadIdx.x, w = tid >> 6, l = tid & 63;
  int wm = w >> 1, wn = w & 1;
  int fr = l & 15, g = l >> 4;

  const bf16x8 *AF, *BGF, *BUF;
  bf16x8* OP;
  int rg0, cg0, kkd0, KCd;

  if (bid < 16 * NRT128) {
    int cb = bid & 15, rt = bid >> 4;
    int e = rt2e[rt]; if (e < 0) return;
    rg0 = rt * 8;
    AF  = (const bf16x8*)xgf;
    BGF = (const bf16x8*)wgf;  BUF = (const bf16x8*)wuf;
    cg0 = e * (I_DIM >> 4) + cb * 8;
    KCd = I_DIM >> 5; kkd0 = cb * 4 + wn * 2;
    OP  = (bf16x8*)interF;
  } else {
    int b2 = bid - 16 * NRT128;
    int cb = b2 & 7, rt = b2 >> 3;
    rg0 = rt * 8;
    AF  = (const bf16x8*)xsf;
    BGF = (const bf16x8*)swgf; BUF = (const bf16x8*)swuf;
    cg0 = cb * 8;
    KCd = IS_DIM >> 5; kkd0 = cb * 4 + wn * 2;
    OP  = (bf16x8*)interS;
  }

  __shared__ ushort_t sm[9][4096];   // 3 bufs x (A, Bg, Bu) = 72KB

  const bf16x8* sa0 = AF  + (size_t)(rg0 + 2 * w)     * KC * 64 + l;
  const bf16x8* sa1 = AF  + (size_t)(rg0 + 2 * w + 1) * KC * 64 + l;
  const bf16x8* sg0 = BGF + (size_t)(cg0 + 2 * w)     * KC * 64 + l;
  const bf16x8* sg1 = BGF + (size_t)(cg0 + 2 * w + 1) * KC * 64 + l;
  const bf16x8* su0 = BUF + (size_t)(cg0 + 2 * w)     * KC * 64 + l;
  const bf16x8* su1 = BUF + (size_t)(cg0 + 2 * w + 1) * KC * 64 + l;
  int s0 = (2 * w) * 512, s1 = (2 * w + 1) * 512;

  f32x4 accg[4][4] = {}, accu[4][4] = {};

  auto stage = [&](int b, int kk) {
    gload16(sa0 + (size_t)kk * 64, &sm[3 * b + 0][s0]);
    gload16(sa1 + (size_t)kk * 64, &sm[3 * b + 0][s1]);
    gload16(sg0 + (size_t)kk * 64, &sm[3 * b + 1][s0]);
    gload16(sg1 + (size_t)kk * 64, &sm[3 * b + 1][s1]);
    gload16(su0 + (size_t)kk * 64, &sm[3 * b + 2][s0]);
    gload16(su1 + (size_t)kk * 64, &sm[3 * b + 2][s1]);
  };
  auto compute = [&](int b) {
    bf16x8 af[4], bg[4], bu[4];
    #pragma unroll
    for (int mi = 0; mi < 4; mi++)
      af[mi] = *(const bf16x8*)&sm[3 * b + 0][(wm * 4 + mi) * 512 + l * 8];
    #pragma unroll
    for (int ni = 0; ni < 4; ni++) {
      bg[ni] = *(const bf16x8*)&sm[3 * b + 1][(wn * 4 + ni) * 512 + l * 8];
      bu[ni] = *(const bf16x8*)&sm[3 * b + 2][(wn * 4 + ni) * 512 + l * 8];
    }
    __builtin_amdgcn_s_setprio(1);
    #pragma unroll
    for (int mi = 0; mi < 4; mi++)
      #pragma unroll
      for (int ni = 0; ni < 4; ni++) {
        accg[mi][ni] = __builtin_amdgcn_mfma_f32_16x16x32_bf16(af[mi], bg[ni], accg[mi][ni], 0, 0, 0);
        accu[mi][ni] = __builtin_amdgcn_mfma_f32_16x16x32_bf16(af[mi], bu[ni], accu[mi][ni], 0, 0, 0);
      }
    __builtin_amdgcn_s_setprio(0);
  };

  stage(0, 0); stage(1, 1); stage(2, 2);
  int b = 0;
  for (int kk = 0; kk < KC - 2; kk++) {          // kk = 0..13
    asm volatile("s_waitcnt vmcnt(12)" ::: "memory");
    __builtin_amdgcn_s_barrier();
    compute(b);
    __builtin_amdgcn_s_barrier();
    if (kk + 3 < KC) stage(b, kk + 3);
    b = (b == 2) ? 0 : b + 1;
  }
  // kk = KC-2
  asm volatile("s_waitcnt vmcnt(6)" ::: "memory");
  __builtin_amdgcn_s_barrier();
  compute(b);
  b = (b == 2) ? 0 : b + 1;
  // kk = KC-1
  asm volatile("s_waitcnt vmcnt(0)" ::: "memory");
  __builtin_amdgcn_s_barrier();
  compute(b);
  __builtin_amdgcn_s_barrier();   // epilogue bounce reuses buffer 0 planes

  // epilogue: silu(g)*u -> per-wave bounce (transpose to FM) -> global FM write
  ushort_t* bw = &sm[0][0] + w * (64 * 72);
  #pragma unroll
  for (int mi = 0; mi < 4; mi++)
    #pragma unroll
    for (int ni = 0; ni < 4; ni++)
      #pragma unroll
      for (int j = 0; j < 4; j++) {
        float gg = accg[mi][ni][j], uu = accu[mi][ni][j];
        float s = (gg / (1.f + expf(-gg))) * uu;
        bw[(mi * 16 + g * 4 + j) * 72 + ni * 16 + fr] = f2bf(s);
      }
  #pragma unroll
  for (int rgi = 0; rgi < 4; rgi++)
    #pragma unroll
    for (int kki = 0; kki < 2; kki++) {
      bf16x8 v = *(const bf16x8*)&bw[(rgi * 16 + (l & 15)) * 72 + kki * 32 + (l >> 4) * 8];
      OP[((size_t)(rg0 + wm * 4 + rgi) * KCd + kkd0 + kki) * 64 + l] = v;
    }
}

// ---------------- 5) down GEMM: 3-deep pipeline, counted vmcnt ----------------
__global__ __launch_bounds__(128, 3) void down10_kernel(
    const ushort_t* __restrict__ interF, const ushort_t* __restrict__ interS,
    const ushort_t* __restrict__ wdf, const ushort_t* __restrict__ swdf,
    float* __restrict__ Dr, float* __restrict__ Ds,
    const int* __restrict__ rg2e)
{
  int bid = blockIdx.x;
  int tid = threadIdx.x, w = tid >> 6, l = tid & 63;
  int fr = l & 15, g = l >> 4;

  const bf16x8 *AF, *BF;
  float* DO;
  int rgA0, cg0, nk, row0, col0;

  if (bid < 4 * NRT64) {
    int cb = bid & 3, rt = bid >> 2;
    int e = rg2e[rt]; if (e < 0) return;
    AF = (const bf16x8*)interF; BF = (const bf16x8*)wdf;
    rgA0 = rt * 4; cg0 = e * (H_DIM >> 4) + cb * 8;
    nk = I_DIM >> 5;   // 64
    row0 = rt * 64; col0 = cb * 128;
    DO = Dr;
  } else {
    int b2 = bid - 4 * NRT64;
    int cb = b2 & 3, rt = b2 >> 2;
    AF = (const bf16x8*)interS; BF = (const bf16x8*)swdf;
    rgA0 = rt * 4; cg0 = cb * 8;
    nk = IS_DIM >> 5;  // 32
    row0 = rt * 64; col0 = cb * 128;
    DO = Ds;
  }

  __shared__ ushort_t sm[3][6144];   // 3 bufs x 12 chunks (4 A + 8 B) = 36KB

  const bf16x8* sa0 = AF + ((size_t)(rgA0 + 2 * w)     * nk) * 64 + l;
  const bf16x8* sa1 = AF + ((size_t)(rgA0 + 2 * w + 1) * nk) * 64 + l;
  const bf16x8* sb0 = BF + ((size_t)(cg0 + 4 * w)      * nk) * 64 + l;
  const bf16x8* sb1 = BF + ((size_t)(cg0 + 4 * w + 1)  * nk) * 64 + l;
  const bf16x8* sb2 = BF + ((size_t)(cg0 + 4 * w + 2)  * nk) * 64 + l;
  const bf16x8* sb3 = BF + ((size_t)(cg0 + 4 * w + 3)  * nk) * 64 + l;

  f32x4 acc[4][4] = {};

  auto stage = [&](int b, int kk) {
    gload16(sa0 + (size_t)kk * 64, &sm[b][(2 * w) * 512]);
    gload16(sa1 + (size_t)kk * 64, &sm[b][(2 * w + 1) * 512]);
    gload16(sb0 + (size_t)kk * 64, &sm[b][(4 + 4 * w) * 512]);
    gload16(sb1 + (size_t)kk * 64, &sm[b][(5 + 4 * w) * 512]);
    gload16(sb2 + (size_t)kk * 64, &sm[b][(6 + 4 * w) * 512]);
    gload16(sb3 + (size_t)kk * 64, &sm[b][(7 + 4 * w) * 512]);
  };
  auto compute = [&](int b) {
    bf16x8 af[4], bf[4];
    #pragma unroll
    for (int mi = 0; mi < 4; mi++)
      af[mi] = *(const bf16x8*)&sm[b][mi * 512 + l * 8];
    #pragma unroll
    for (int ni = 0; ni < 4; ni++)
      bf[ni] = *(const bf16x8*)&sm[b][(4 + w * 4 + ni) * 512 + l * 8];
    __builtin_amdgcn_s_setprio(1);
    #pragma unroll
    for (int mi = 0; mi < 4; mi++)
      #pragma unroll
      for (int ni = 0; ni < 4; ni++)
        acc[mi][ni] = __builtin_amdgcn_mfma_f32_16x16x32_bf16(af[mi], bf[ni], acc[mi][ni], 0, 0, 0);
    __builtin_amdgcn_s_setprio(0);
  };

  stage(0, 0); stage(1, 1); stage(2, 2);
  int b = 0;
  for (int kk = 0; kk < nk - 2; kk++) {
    asm volatile("s_waitcnt vmcnt(12)" ::: "memory");
    __builtin_amdgcn_s_barrier();
    compute(b);
    __builtin_amdgcn_s_barrier();
    if (kk + 3 < nk) stage(b, kk + 3);
    b = (b == 2) ? 0 : b + 1;
  }
  asm volatile("s_waitcnt vmcnt(6)" ::: "memory");
  __builtin_amdgcn_s_barrier();
  compute(b);
  b = (b == 2) ? 0 : b + 1;
  asm volatile("s_waitcnt vmcnt(0)" ::: "memory");
  __builtin_amdgcn_s_barrier();
  compute(b);

  #pragma unroll
  for (int mi = 0; mi < 4; mi++)
    #pragma unroll
    for (int ni = 0; ni < 4; ni++)
      #pragma unroll
      for (int j = 0; j < 4; j++)
        DO[(size_t)(row0 + mi * 16 + g * 4 + j) * H_DIM + col0 + w * 64 + ni * 16 + fr]
            = acc[mi][ni][j];
}

// ---------------- 6) combine: out[t] = w0*Dr[r0] + w1*Dr[r1] + Ds[t] ----------
__global__ __launch_bounds__(128) void combine_kernel(
    const float* __restrict__ Dr, const float* __restrict__ Ds,
    const int* __restrict__ trow, const float* __restrict__ topk_w,
    float* __restrict__ out)
{
  int t = blockIdx.x, c = threadIdx.x;
  int r0 = trow[t * 2], r1 = trow[t * 2 + 1];
  float w0 = topk_w[t * 2], w1 = topk_w[t * 2 + 1];
  float4 a = ((const float4*)(Dr + (size_t)r0 * H_DIM))[c];
  float4 b = ((const float4*)(Dr + (size_t)r1 * H_DIM))[c];
  float4 s = ((const float4*)(Ds + (size_t)t * H_DIM))[c];
  float4 r;
  r.x = w0 * a.x + w1 * b.x + s.x;
  r.y = w0 * a.y + w1 * b.y + s.y;
  r.z = w0 * a.z + w1 * b.z + s.z;
  r.w = w0 * a.w + w1 * b.w + s.w;
  ((float4*)(out + (size_t)t * H_DIM))[c] = r;
}

// ---------------- launch ----------------
extern "C" void kernel_launch(void* const* d_in, const int* in_sizes, int n_in,
                              void* d_out, int out_size, void* d_ws, size_t ws_size,
                              hipStream_t stream) {
  const float* x       = (const float*)d_in[0];
  const float* gate_w  = (const float*)d_in[1];
  const float* w_gate  = (const float*)d_in[2];
  const float* w_up    = (const float*)d_in[3];
  const float* w_down  = (const float*)d_in[4];
  const float* sw_gate = (const float*)d_in[5];
  const float* sw_up   = (const float*)d_in[6];
  const float* sw_down = (const float*)d_in[7];
  float* out = (float*)d_out;

  char* ws = (char*)d_ws;
  int*   counts    = (int*)ws;                      // 16
  int*   cursor    = (int*)(ws + 64);               // 16
  int*   offp      = (int*)(ws + 128);              // 17
  int*   rt2e      = (int*)(ws + 256);              // 48
  int*   rg2e      = (int*)(ws + 448);              // 96
  int*   topk_idx  = (int*)(ws + 832);              // 4096
  float* topk_w    = (float*)(ws + 17216);          // 4096
  int*   trow      = (int*)(ws + 33600);            // 4096
  int*   row_token = (int*)(ws + 49984);            // RPMAX
  size_t off = 49984 + (size_t)RPMAX * 4;
  off = (off + 255) & ~(size_t)255;
  float*    logits = (float*)(ws + off);    off += (size_t)T_TOK * E_NUM * 4;       // 128 KiB
  ushort_t* xgf  = (ushort_t*)(ws + off); off += (size_t)RPMAX * H_DIM * 2;         // 6 MiB
  ushort_t* xsf  = (ushort_t*)(ws + off); off += (size_t)T_TOK * H_DIM * 2;         // 2 MiB
  ushort_t* wgf  = (ushort_t*)(ws + off); off += (size_t)E_NUM * I_DIM * H_DIM * 2; // 32 MiB
  ushort_t* wuf  = (ushort_t*)(ws + off); off += (size_t)E_NUM * I_DIM * H_DIM * 2; // 32 MiB
  ushort_t* wdf  = (ushort_t*)(ws + off); off += (size_t)E_NUM * H_DIM * I_DIM * 2; // 32 MiB
  ushort_t* swgf = (ushort_t*)(ws + off); off += (size_t)IS_DIM * H_DIM * 2;        // 1 MiB
  ushort_t* swuf = (ushort_t*)(ws + off); off += (size_t)IS_DIM * H_DIM * 2;        // 1 MiB
  ushort_t* swdf = (ushort_t*)(ws + off); off += (size_t)H_DIM * IS_DIM * 2;        // 1 MiB
  ushort_t* interF = (ushort_t*)(ws + off); off += (size_t)RPMAX * I_DIM * 2;       // 24 MiB
  ushort_t* interS = (ushort_t*)(ws + off); off += (size_t)T_TOK * IS_DIM * 2;      // 4 MiB
  float*    Dr     = (float*)(ws + off);    off += (size_t)RPMAX * H_DIM * 4;       // 12 MiB
  float*    Ds     = (float*)(ws + off);    off += (size_t)T_TOK * H_DIM * 4;       // 4 MiB

  hipMemsetAsync(counts, 0, 64, stream);
  // gate split: logits GEMV -> per-token softmax/top2 + histogram
  logits_kernel<<<T_TOK / 16, 256, 0, stream>>>(x, gate_w, logits);
  topk_kernel<<<T_TOK / 256, 256, 0, stream>>>(logits, topk_idx, topk_w, counts);
  offsets_kernel<<<1, 128, 0, stream>>>(counts, offp, cursor, rt2e, rg2e);
  initrows_kernel<<<RPMAX / 256, 256, 0, stream>>>(row_token);
  scatter_kernel<<<(T_TOK + 255) / 256, 256, 0, stream>>>(topk_idx, topk_w, offp, cursor,
                                                          row_token, trow);
  // A-operands into FM bf16
  gatherA_kernel<4><<<RPMAX * H_DIM / 8 / 256, 256, 0, stream>>>(
      x, row_token, xgf, RPMAX * H_DIM / 8, H_DIM);
  gatherA_kernel<4><<<T_TOK * H_DIM / 8 / 256, 256, 0, stream>>>(
      x, nullptr, xsf, T_TOK * H_DIM / 8, H_DIM);
  // weights into FM bf16 (LDS-transposed: coalesced reads AND writes)
  permw2_kernel<4><<<E_NUM * I_DIM / 16, 256, 0, stream>>>(w_gate, wgf);
  permw2_kernel<4><<<E_NUM * I_DIM / 16, 256, 0, stream>>>(w_up,   wuf);
  permw2_kernel<6><<<E_NUM * H_DIM / 16, 256, 0, stream>>>(w_down, wdf);
  permw2_kernel<4><<<IS_DIM / 16, 256, 0, stream>>>(sw_gate, swgf);
  permw2_kernel<4><<<IS_DIM / 16, 256, 0, stream>>>(sw_up,   swuf);
  permw2_kernel<5><<<H_DIM / 16, 256, 0, stream>>>(sw_down, swdf);

  // GU: routed (16 cb x 48 rt = 768) + shared (8 cb x 16 rt = 128)
  gu10_kernel<<<16 * NRT128 + 8 * 16, 256, 0, stream>>>(
      xgf, xsf, wgf, wuf, swgf, swuf, interF, interS, rt2e);
  // down: routed (4 cb x 96 rt = 384) + shared (4 cb x 32 rt = 128)
  down10_kernel<<<4 * NRT64 + 4 * 32, 128, 0, stream>>>(
      interF, interS, wdf, swdf, Dr, Ds, rg2e);
  // combine
  combine_kernel<<<T_TOK, 128, 0, stream>>>(Dr, Ds, trow, topk_w, out);
}